// Round 1
// baseline (4567.441 us; speedup 1.0000x reference)
//
#include <hip/hip_runtime.h>
#include <hip/hip_bf16.h>
#include <cmath>

#define S_LEN 2048
#define D_MODEL 2048
#define N_HEADS 16
#define Q_LORA 1536
#define KV_LORA 512
#define NOPE 128
#define ROPE_D 64
#define VD 128
#define QHD 192

// ---------------------------------------------------------------------------
// Generic tiled f32 GEMM: C[M,N] = A[M,K] @ W[N,K]^T
// 64x64 tile per block, 256 threads, 4x4 accumulators per thread, K-step 16.
// All M,N used here are multiples of 64 and K multiples of 16 -> no guards.
// ---------------------------------------------------------------------------
__global__ __launch_bounds__(256) void gemm_bt(const float* __restrict__ A,
                                               const float* __restrict__ W,
                                               float* __restrict__ C,
                                               int M, int N, int K) {
  __shared__ float As[16][65];  // +1 pad: avoids 16-way bank conflict on write
  __shared__ float Ws[16][65];
  const int tid = threadIdx.x;
  const int tx = tid & 15, ty = tid >> 4;
  const int arow = blockIdx.y * 64, wrow = blockIdx.x * 64;
  float acc[4][4] = {};
  for (int k0 = 0; k0 < K; k0 += 16) {
#pragma unroll
    for (int e = 0; e < 4; ++e) {
      int idx = e * 256 + tid;
      int r = idx >> 4, kk = idx & 15;
      As[kk][r] = A[(size_t)(arow + r) * K + k0 + kk];
      Ws[kk][r] = W[(size_t)(wrow + r) * K + k0 + kk];
    }
    __syncthreads();
#pragma unroll
    for (int kk = 0; kk < 16; ++kk) {
      float a[4], b[4];
#pragma unroll
      for (int i = 0; i < 4; ++i) a[i] = As[kk][ty * 4 + i];
#pragma unroll
      for (int j = 0; j < 4; ++j) b[j] = Ws[kk][tx * 4 + j];
#pragma unroll
      for (int i = 0; i < 4; ++i)
#pragma unroll
        for (int j = 0; j < 4; ++j) acc[i][j] += a[i] * b[j];
    }
    __syncthreads();
  }
#pragma unroll
  for (int i = 0; i < 4; ++i)
#pragma unroll
    for (int j = 0; j < 4; ++j)
      C[(size_t)(arow + ty * 4 + i) * N + wrow + tx * 4 + j] = acc[i][j];
}

// ---------------------------------------------------------------------------
// RMSNorm over last dim. One block (256 thr) per row. Safe in-place
// (each thread writes exactly the indices it reads; variance uses a barrier).
// ---------------------------------------------------------------------------
__global__ __launch_bounds__(256) void rmsnorm_kernel(const float* __restrict__ src, int src_ld,
                                                      const float* __restrict__ w,
                                                      float* __restrict__ dst, int dst_ld,
                                                      int dim) {
  const int row = blockIdx.x;
  const float* x = src + (size_t)row * src_ld;
  float ss = 0.f;
  for (int i = threadIdx.x; i < dim; i += 256) {
    float v = x[i];
    ss += v * v;
  }
#pragma unroll
  for (int off = 32; off; off >>= 1) ss += __shfl_xor(ss, off);
  __shared__ float red[4];
  const int wv = threadIdx.x >> 6, ln = threadIdx.x & 63;
  if (ln == 0) red[wv] = ss;
  __syncthreads();
  const float tot = red[0] + red[1] + red[2] + red[3];
  const float scale = rsqrtf(tot / (float)dim + 1e-6f);
  for (int i = threadIdx.x; i < dim; i += 256) {
    dst[(size_t)row * dst_ld + i] = w[i] * (x[i] * scale);
  }
}

// ---------------------------------------------------------------------------
// RoPE (deinterleave + rotate-half folded together), in place.
//   out[j]    = x[2j]*cos - x[2j+1]*sin        (j in [0,32))
//   out[j+32] = x[2j+1]*cos + x[2j]*sin
// Applied to the 64-wide pe slice of each of 16 q heads and to k_pe in ckv.
// Block = 32 threads (thread j handles pair j); barriers guard the in-place
// read->write overlap across threads.
// ---------------------------------------------------------------------------
__global__ void rope_kernel(float* __restrict__ q, float* __restrict__ ckv,
                            const int* __restrict__ pos_ids) {
  const int s = blockIdx.x;
  const int j = threadIdx.x;  // 0..31
  const float t = (float)pos_ids[s];
  const float invf = powf(50000.0f, -(float)(2 * j) / 64.0f);
  const float ang = t * invf;
  const float c = cosf(ang), sn = sinf(ang);
  for (int h = 0; h < N_HEADS; ++h) {
    float* base = q + (size_t)s * (N_HEADS * QHD) + h * QHD + NOPE;
    const float x0 = base[2 * j], x1 = base[2 * j + 1];
    __syncthreads();
    base[j] = x0 * c - x1 * sn;
    base[32 + j] = x1 * c + x0 * sn;
    __syncthreads();
  }
  float* base = ckv + (size_t)s * (KV_LORA + ROPE_D) + KV_LORA;
  const float x0 = base[2 * j], x1 = base[2 * j + 1];
  __syncthreads();
  base[j] = x0 * c - x1 * sn;
  base[32 + j] = x1 * c + x0 * sn;
}

// ---------------------------------------------------------------------------
// Causal attention, online softmax. One wave per (head, q-row).
// q:   (S, 16*192)  [pe already roped]
// kv:  (S, 16*256)  cols h*256+[0,128) = k_nope, [128,256) = value
// ckv: (S, 576)     cols 512+[0,64) = roped k_pe (shared across heads)
// out: (S, 16*128)  col h*128+d  (i.e. already (b,s,h,vd) -> flat)
// ---------------------------------------------------------------------------
__global__ __launch_bounds__(256) void attn_kernel(const float* __restrict__ q,
                                                   const float* __restrict__ kv,
                                                   const float* __restrict__ ckv,
                                                   float* __restrict__ out) {
  const int wave = threadIdx.x >> 6;
  const int lane = threadIdx.x & 63;
  const int h = blockIdx.y;
  const int srow = blockIdx.x * 4 + wave;
  const float scale = 0.07216878364870323f;  // 192^-0.5
  const size_t qoff = (size_t)srow * (N_HEADS * QHD) + h * QHD;
  const float q0 = q[qoff + lane] * scale;
  const float q1 = q[qoff + 64 + lane] * scale;
  const float q2 = q[qoff + 128 + lane] * scale;
  float m = -INFINITY, l = 0.f, o0 = 0.f, o1 = 0.f;
  const float* kvh = kv + h * 256;
  for (int k = 0; k <= srow; ++k) {
    const float* krow = kvh + (size_t)k * (N_HEADS * 256);
    const float* perow = ckv + (size_t)k * (KV_LORA + ROPE_D) + KV_LORA;
    float partial = q0 * krow[lane] + q1 * krow[64 + lane] + q2 * perow[lane];
#pragma unroll
    for (int off = 32; off; off >>= 1) partial += __shfl_xor(partial, off);
    const float s = partial;
    const float mn = fmaxf(m, s);
    const float corr = expf(m - mn);  // first iter: exp(-inf)=0
    const float p = expf(s - mn);
    l = l * corr + p;
    o0 = o0 * corr + p * krow[128 + lane];
    o1 = o1 * corr + p * krow[192 + lane];
    m = mn;
  }
  const float inv_l = 1.f / l;
  out[(size_t)srow * (N_HEADS * VD) + h * VD + lane] = o0 * inv_l;
  out[(size_t)srow * (N_HEADS * VD) + h * VD + 64 + lane] = o1 * inv_l;
}

// ---------------------------------------------------------------------------
extern "C" void kernel_launch(void* const* d_in, const int* in_sizes, int n_in,
                              void* d_out, int out_size, void* d_ws, size_t ws_size,
                              hipStream_t stream) {
  const float* hidden   = (const float*)d_in[0];
  const int*   pos      = (const int*)d_in[1];
  const float* q_a_w    = (const float*)d_in[2];
  const float* q_a_ln_w = (const float*)d_in[3];
  const float* q_b_w    = (const float*)d_in[4];
  const float* kv_a_w   = (const float*)d_in[5];
  const float* kv_a_ln_w= (const float*)d_in[6];
  const float* kv_b_w   = (const float*)d_in[7];
  const float* o_w      = (const float*)d_in[8];
  float* out = (float*)d_out;

  // workspace layout (floats): total ~24.25M floats = ~97 MB
  float* ws    = (float*)d_ws;
  float* q_a   = ws;                    // 2048*1536
  float* qbuf  = q_a + 2048 * 1536;     // 2048*3072
  float* ckv   = qbuf + 2048 * 3072;    // 2048*576
  float* ckvn  = ckv + 2048 * 576;      // 2048*512
  float* kvbuf = ckvn + 2048 * 512;     // 2048*4096
  float* attn  = kvbuf + 2048 * 4096;   // 2048*2048
  (void)in_sizes; (void)n_in; (void)out_size; (void)ws_size;

  const dim3 b256(256);

  // q_a = hidden @ q_a_w.T
  gemm_bt<<<dim3(Q_LORA / 64, S_LEN / 64), b256, 0, stream>>>(hidden, q_a_w, q_a, S_LEN, Q_LORA, D_MODEL);
  // rmsnorm in place
  rmsnorm_kernel<<<S_LEN, 256, 0, stream>>>(q_a, Q_LORA, q_a_ln_w, q_a, Q_LORA, Q_LORA);
  // q = q_a @ q_b_w.T
  gemm_bt<<<dim3(N_HEADS * QHD / 64, S_LEN / 64), b256, 0, stream>>>(q_a, q_b_w, qbuf, S_LEN, N_HEADS * QHD, Q_LORA);
  // ckv = hidden @ kv_a_w.T
  gemm_bt<<<dim3((KV_LORA + ROPE_D) / 64, S_LEN / 64), b256, 0, stream>>>(hidden, kv_a_w, ckv, S_LEN, KV_LORA + ROPE_D, D_MODEL);
  // ckvn = rmsnorm(ckv[:, :512])
  rmsnorm_kernel<<<S_LEN, 256, 0, stream>>>(ckv, KV_LORA + ROPE_D, kv_a_ln_w, ckvn, KV_LORA, KV_LORA);
  // rope on q_pe (16 heads) and k_pe (in ckv)
  rope_kernel<<<S_LEN, 32, 0, stream>>>(qbuf, ckv, pos);
  // kv = ckvn @ kv_b_w.T
  gemm_bt<<<dim3(N_HEADS * (NOPE + VD) / 64, S_LEN / 64), b256, 0, stream>>>(ckvn, kv_b_w, kvbuf, S_LEN, N_HEADS * (NOPE + VD), KV_LORA);
  // attention
  attn_kernel<<<dim3(S_LEN / 4, N_HEADS), b256, 0, stream>>>(qbuf, kvbuf, ckv, attn);
  // out = attn @ o_w.T
  gemm_bt<<<dim3(D_MODEL / 64, S_LEN / 64), b256, 0, stream>>>(attn, o_w, out, S_LEN, D_MODEL, D_MODEL);
}

// Round 2
// 1858.516 us; speedup vs baseline: 2.4576x; 2.4576x over previous
//
#include <hip/hip_runtime.h>
#include <hip/hip_bf16.h>
#include <cmath>

#define S_LEN 2048
#define D_MODEL 2048
#define N_HEADS 16
#define Q_LORA 1536
#define KV_LORA 512
#define NOPE 128
#define ROPE_D 64
#define VD 128
#define QHD 192

typedef __attribute__((ext_vector_type(8))) short bf16x8;
typedef __attribute__((ext_vector_type(4))) float f32x4;

struct V8 { uint2 lo, hi; };

static __device__ __forceinline__ unsigned short f2u(float x) {
  union { float f; unsigned u; } v; v.f = x;
  unsigned r = v.u + 0x7fffu + ((v.u >> 16) & 1u);  // RNE
  return (unsigned short)(r >> 16);
}

// ---------------------------------------------------------------------------
// f32 tiled GEMM: C[M,N] = A[M,K] @ W[N,K]^T  (unchanged from round 1)
// ---------------------------------------------------------------------------
__global__ __launch_bounds__(256) void gemm_bt(const float* __restrict__ A,
                                               const float* __restrict__ W,
                                               float* __restrict__ C,
                                               int M, int N, int K) {
  __shared__ float As[16][65];
  __shared__ float Ws[16][65];
  const int tid = threadIdx.x;
  const int tx = tid & 15, ty = tid >> 4;
  const int arow = blockIdx.y * 64, wrow = blockIdx.x * 64;
  float acc[4][4] = {};
  for (int k0 = 0; k0 < K; k0 += 16) {
#pragma unroll
    for (int e = 0; e < 4; ++e) {
      int idx = e * 256 + tid;
      int r = idx >> 4, kk = idx & 15;
      As[kk][r] = A[(size_t)(arow + r) * K + k0 + kk];
      Ws[kk][r] = W[(size_t)(wrow + r) * K + k0 + kk];
    }
    __syncthreads();
#pragma unroll
    for (int kk = 0; kk < 16; ++kk) {
      float a[4], b[4];
#pragma unroll
      for (int i = 0; i < 4; ++i) a[i] = As[kk][ty * 4 + i];
#pragma unroll
      for (int j = 0; j < 4; ++j) b[j] = Ws[kk][tx * 4 + j];
#pragma unroll
      for (int i = 0; i < 4; ++i)
#pragma unroll
        for (int j = 0; j < 4; ++j) acc[i][j] += a[i] * b[j];
    }
    __syncthreads();
  }
#pragma unroll
  for (int i = 0; i < 4; ++i)
#pragma unroll
    for (int j = 0; j < 4; ++j)
      C[(size_t)(arow + ty * 4 + i) * N + wrow + tx * 4 + j] = acc[i][j];
}

// ---------------------------------------------------------------------------
// RMSNorm (unchanged)
// ---------------------------------------------------------------------------
__global__ __launch_bounds__(256) void rmsnorm_kernel(const float* __restrict__ src, int src_ld,
                                                      const float* __restrict__ w,
                                                      float* __restrict__ dst, int dst_ld,
                                                      int dim) {
  const int row = blockIdx.x;
  const float* x = src + (size_t)row * src_ld;
  float ss = 0.f;
  for (int i = threadIdx.x; i < dim; i += 256) {
    float v = x[i];
    ss += v * v;
  }
#pragma unroll
  for (int off = 32; off; off >>= 1) ss += __shfl_xor(ss, off);
  __shared__ float red[4];
  const int wv = threadIdx.x >> 6, ln = threadIdx.x & 63;
  if (ln == 0) red[wv] = ss;
  __syncthreads();
  const float tot = red[0] + red[1] + red[2] + red[3];
  const float scale = rsqrtf(tot / (float)dim + 1e-6f);
  for (int i = threadIdx.x; i < dim; i += 256) {
    dst[(size_t)row * dst_ld + i] = w[i] * (x[i] * scale);
  }
}

// ---------------------------------------------------------------------------
// RoPE (unchanged)
// ---------------------------------------------------------------------------
__global__ void rope_kernel(float* __restrict__ q, float* __restrict__ ckv,
                            const int* __restrict__ pos_ids) {
  const int s = blockIdx.x;
  const int j = threadIdx.x;  // 0..31
  const float t = (float)pos_ids[s];
  const float invf = powf(50000.0f, -(float)(2 * j) / 64.0f);
  const float ang = t * invf;
  const float c = cosf(ang), sn = sinf(ang);
  for (int h = 0; h < N_HEADS; ++h) {
    float* base = q + (size_t)s * (N_HEADS * QHD) + h * QHD + NOPE;
    const float x0 = base[2 * j], x1 = base[2 * j + 1];
    __syncthreads();
    base[j] = x0 * c - x1 * sn;
    base[32 + j] = x1 * c + x0 * sn;
    __syncthreads();
  }
  float* base = ckv + (size_t)s * (KV_LORA + ROPE_D) + KV_LORA;
  const float x0 = base[2 * j], x1 = base[2 * j + 1];
  __syncthreads();
  base[j] = x0 * c - x1 * sn;
  base[32 + j] = x1 * c + x0 * sn;
}

// ---------------------------------------------------------------------------
// bf16 conversions for attention
// Qb: (H, S, 192) pre-scaled by 192^-0.5     (reads qbuf)
// Kb: (H, S, 192) = [k_nope | roped k_pe]    (reads kvbuf, ckv)
// Vt: (H, 128, S) transposed V               (reads kvbuf)
// ---------------------------------------------------------------------------
__global__ __launch_bounds__(256) void build_q(const float* __restrict__ qbuf,
                                               unsigned short* __restrict__ Qb) {
  const int s = blockIdx.x, h = blockIdx.y, d = threadIdx.x;
  if (d >= 192) return;
  const float v = qbuf[(size_t)s * (N_HEADS * QHD) + h * QHD + d] * 0.07216878364870323f;
  Qb[((size_t)h * S_LEN + s) * QHD + d] = f2u(v);
}

__global__ __launch_bounds__(256) void build_k(const float* __restrict__ kvbuf,
                                               const float* __restrict__ ckv,
                                               unsigned short* __restrict__ Kb) {
  const int s = blockIdx.x, h = blockIdx.y, d = threadIdx.x;
  if (d >= 192) return;
  const float v = (d < NOPE) ? kvbuf[(size_t)s * (N_HEADS * 256) + h * 256 + d]
                             : ckv[(size_t)s * (KV_LORA + ROPE_D) + KV_LORA + (d - NOPE)];
  Kb[((size_t)h * S_LEN + s) * QHD + d] = f2u(v);
}

__global__ __launch_bounds__(256) void build_vt(const float* __restrict__ kvbuf,
                                                unsigned short* __restrict__ Vt) {
  __shared__ float t[32][33];
  const int s0 = blockIdx.x * 32, d0 = blockIdx.y * 32, h = blockIdx.z;
  const int tx = threadIdx.x & 31, ty = threadIdx.x >> 5;  // 8 rows/pass
#pragma unroll
  for (int i = 0; i < 4; ++i) {
    const int s = s0 + ty + i * 8;
    t[ty + i * 8][tx] = kvbuf[(size_t)s * (N_HEADS * 256) + h * 256 + NOPE + d0 + tx];
  }
  __syncthreads();
#pragma unroll
  for (int i = 0; i < 4; ++i) {
    const int d = d0 + ty + i * 8;
    Vt[((size_t)h * VD + d) * S_LEN + s0 + tx] = f2u(t[tx][ty + i * 8]);
  }
}

// ---------------------------------------------------------------------------
// MFMA flash attention. One wave = 16 q rows of one head; 4 waves/block.
// Scores computed swapped: C = mfma(A=K_tile, B=Q^T) -> C[k][q], q = lane&15.
// O^T = mfma(A=V^T, B=P) with identical custom k-mapping on both operands
// (robust to HW k-permutation), P packed in-lane from the score fragment.
// ---------------------------------------------------------------------------
__global__ __launch_bounds__(256) void flash_attn(const unsigned short* __restrict__ Qb,
                                                  const unsigned short* __restrict__ Kb,
                                                  const unsigned short* __restrict__ Vt,
                                                  float* __restrict__ out) {
  const int wave = threadIdx.x >> 6, lane = threadIdx.x & 63;
  const int g = lane >> 4, col = lane & 15;
  const int h = blockIdx.y;
  const int qtile = (int)(gridDim.x - 1 - blockIdx.x);  // heavy blocks first
  const int qw = qtile * 64 + wave * 16;
  const int qr = qw + col;

  bf16x8 qf[6];
  {
    const unsigned short* qrow = Qb + ((size_t)h * S_LEN + qw + col) * QHD + g * 8;
#pragma unroll
    for (int t = 0; t < 6; ++t) qf[t] = *(const bf16x8*)(qrow + t * 32);
  }
  f32x4 o[8];
#pragma unroll
  for (int i = 0; i < 8; ++i) o[i] = (f32x4){0.f, 0.f, 0.f, 0.f};
  float m = -1e30f, l = 0.f;

  const unsigned short* kbase = Kb + (size_t)h * S_LEN * QHD;
  const unsigned short* vbase = Vt + (size_t)h * VD * S_LEN;
  const int nblk = (qw + 16 + 31) >> 5;

  for (int kb = 0; kb < nblk; ++kb) {
    const int k0 = kb * 32;
    f32x4 c0 = (f32x4){0.f, 0.f, 0.f, 0.f}, c1 = (f32x4){0.f, 0.f, 0.f, 0.f};
    const unsigned short* ka0 = kbase + (size_t)(k0 + col) * QHD + g * 8;
    const unsigned short* ka1 = ka0 + 16 * QHD;
#pragma unroll
    for (int t = 0; t < 6; ++t) {
      bf16x8 a0 = *(const bf16x8*)(ka0 + t * 32);
      bf16x8 a1 = *(const bf16x8*)(ka1 + t * 32);
      c0 = __builtin_amdgcn_mfma_f32_16x16x32_bf16(a0, qf[t], c0, 0, 0, 0);
      c1 = __builtin_amdgcn_mfma_f32_16x16x32_bf16(a1, qf[t], c1, 0, 0, 0);
    }
    // causal mask + online softmax (q = lane&15; k = k0 + 16*frag + 4g + r)
    float s0[4], s1[4];
#pragma unroll
    for (int r = 0; r < 4; ++r) {
      const int kk = k0 + 4 * g + r;
      s0[r] = (kk <= qr) ? c0[r] : -1e30f;
      s1[r] = (kk + 16 <= qr) ? c1[r] : -1e30f;
    }
    float bm = fmaxf(fmaxf(fmaxf(s0[0], s0[1]), fmaxf(s0[2], s0[3])),
                     fmaxf(fmaxf(s1[0], s1[1]), fmaxf(s1[2], s1[3])));
    bm = fmaxf(bm, __shfl_xor(bm, 16));
    bm = fmaxf(bm, __shfl_xor(bm, 32));
    const float mn = fmaxf(m, bm);
    const float corr = __expf(m - mn);
    float ps = 0.f;
    bf16x8 pb;
#pragma unroll
    for (int r = 0; r < 4; ++r) {
      const float p0 = __expf(s0[r] - mn);
      const float p1 = __expf(s1[r] - mn);
      ps += p0 + p1;
      pb[r] = (short)f2u(p0);      // B elem j<4  -> k = k0 + 4g + j
      pb[4 + r] = (short)f2u(p1);  // B elem j>=4 -> k = k0 + 16 + 4g + (j-4)
    }
    ps += __shfl_xor(ps, 16);
    ps += __shfl_xor(ps, 32);
    l = l * corr + ps;
    m = mn;
#pragma unroll
    for (int i = 0; i < 8; ++i) {
      o[i][0] *= corr; o[i][1] *= corr; o[i][2] *= corr; o[i][3] *= corr;
    }
    // O^T += V^T * P   (A elem j: k = k0 + 4g + (j&3) + 16*(j>>2) — same map)
#pragma unroll
    for (int db = 0; db < 8; ++db) {
      const unsigned short* vrow = vbase + (size_t)(db * 16 + col) * S_LEN + k0 + 4 * g;
      V8 tmp;
      tmp.lo = *(const uint2*)(vrow);
      tmp.hi = *(const uint2*)(vrow + 16);
      const bf16x8 va = __builtin_bit_cast(bf16x8, tmp);
      o[db] = __builtin_amdgcn_mfma_f32_16x16x32_bf16(va, pb, o[db], 0, 0, 0);
    }
  }
  const float inv = 1.f / l;
  float* orow = out + (size_t)(qw + col) * (N_HEADS * VD) + h * VD;
#pragma unroll
  for (int db = 0; db < 8; ++db)
#pragma unroll
    for (int r = 0; r < 4; ++r)
      orow[db * 16 + 4 * g + r] = o[db][r] * inv;
}

// ---------------------------------------------------------------------------
extern "C" void kernel_launch(void* const* d_in, const int* in_sizes, int n_in,
                              void* d_out, int out_size, void* d_ws, size_t ws_size,
                              hipStream_t stream) {
  const float* hidden    = (const float*)d_in[0];
  const int*   pos       = (const int*)d_in[1];
  const float* q_a_w     = (const float*)d_in[2];
  const float* q_a_ln_w  = (const float*)d_in[3];
  const float* q_b_w     = (const float*)d_in[4];
  const float* kv_a_w    = (const float*)d_in[5];
  const float* kv_a_ln_w = (const float*)d_in[6];
  const float* kv_b_w    = (const float*)d_in[7];
  const float* o_w       = (const float*)d_in[8];
  float* out = (float*)d_out;

  // f32 workspace (floats), 24.25M total = 97 MB:
  float* ws    = (float*)d_ws;
  float* q_a   = ws;                     // 3,145,728
  float* qbuf  = ws + 3145728;           // 6,291,456
  float* ckv   = ws + 9437184;           // 1,179,648
  float* ckvn  = ws + 10616832;          // 1,048,576
  float* kvbuf = ws + 11665408;          // 8,388,608
  float* attn  = ws + 20054016;          // 4,194,304
  // bf16 overlays on dead regions (valid by launch order):
  unsigned short* Qb = (unsigned short*)(ws);            // over q_a   (12.6 MB)
  unsigned short* Kb = (unsigned short*)(ws + 3145728);  // over qbuf  (12.6 MB)
  unsigned short* Vt = (unsigned short*)(ws + 6291456);  // over qbuf  ( 8.4 MB)
  (void)in_sizes; (void)n_in; (void)out_size; (void)ws_size;

  const dim3 b256(256);

  gemm_bt<<<dim3(Q_LORA / 64, S_LEN / 64), b256, 0, stream>>>(hidden, q_a_w, q_a, S_LEN, Q_LORA, D_MODEL);
  rmsnorm_kernel<<<S_LEN, 256, 0, stream>>>(q_a, Q_LORA, q_a_ln_w, q_a, Q_LORA, Q_LORA);
  gemm_bt<<<dim3(N_HEADS * QHD / 64, S_LEN / 64), b256, 0, stream>>>(q_a, q_b_w, qbuf, S_LEN, N_HEADS * QHD, Q_LORA);
  gemm_bt<<<dim3((KV_LORA + ROPE_D) / 64, S_LEN / 64), b256, 0, stream>>>(hidden, kv_a_w, ckv, S_LEN, KV_LORA + ROPE_D, D_MODEL);
  rmsnorm_kernel<<<S_LEN, 256, 0, stream>>>(ckv, KV_LORA + ROPE_D, kv_a_ln_w, ckvn, KV_LORA, KV_LORA);
  rope_kernel<<<S_LEN, 32, 0, stream>>>(qbuf, ckv, pos);
  gemm_bt<<<dim3(N_HEADS * (NOPE + VD) / 64, S_LEN / 64), b256, 0, stream>>>(ckvn, kv_b_w, kvbuf, S_LEN, N_HEADS * (NOPE + VD), KV_LORA);

  // bf16 staging (order matters: build_q consumes qbuf before Kb/Vt overwrite it)
  build_q<<<dim3(S_LEN, N_HEADS), b256, 0, stream>>>(qbuf, Qb);
  build_k<<<dim3(S_LEN, N_HEADS), b256, 0, stream>>>(kvbuf, ckv, Kb);
  build_vt<<<dim3(S_LEN / 32, VD / 32, N_HEADS), b256, 0, stream>>>(kvbuf, Vt);

  flash_attn<<<dim3(S_LEN / 64, N_HEADS), b256, 0, stream>>>(Qb, Kb, Vt, attn);

  gemm_bt<<<dim3(D_MODEL / 64, S_LEN / 64), b256, 0, stream>>>(attn, o_w, out, S_LEN, D_MODEL, D_MODEL);
}

// Round 3
// 597.414 us; speedup vs baseline: 7.6454x; 3.1109x over previous
//
#include <hip/hip_runtime.h>
#include <hip/hip_bf16.h>
#include <cmath>

#define S_LEN 2048
#define D_MODEL 2048
#define N_HEADS 16
#define Q_LORA 1536
#define KV_LORA 512
#define NOPE 128
#define ROPE_D 64
#define VD 128
#define QHD 192

typedef __attribute__((ext_vector_type(8))) short bf16x8;
typedef __attribute__((ext_vector_type(4))) float f32x4;
typedef __attribute__((ext_vector_type(4))) unsigned short u16x4;

struct V8 { uint2 lo, hi; };

static __device__ __forceinline__ unsigned short f2u(float x) {
  union { float f; unsigned u; } v; v.f = x;
  unsigned r = v.u + 0x7fffu + ((v.u >> 16) & 1u);  // RNE
  return (unsigned short)(r >> 16);
}
static __device__ __forceinline__ float u2f(unsigned short x) {
  union { unsigned u; float f; } v; v.u = ((unsigned)x) << 16;
  return v.f;
}

#define AS1 __attribute__((address_space(1)))
#define AS3 __attribute__((address_space(3)))
static __device__ __forceinline__ void gload_lds16(const unsigned short* g, unsigned short* l) {
  __builtin_amdgcn_global_load_lds((const AS1 unsigned int*)g, (AS3 unsigned int*)l, 16, 0, 0);
}

// ---------------------------------------------------------------------------
// f32 -> bf16 convert (optionally scaled). n4 = elements/4.
// ---------------------------------------------------------------------------
__global__ __launch_bounds__(256) void conv_bf16(const float* __restrict__ src,
                                                 unsigned short* __restrict__ dst,
                                                 int n4, float scale) {
  for (int i = blockIdx.x * 256 + threadIdx.x; i < n4; i += gridDim.x * 256) {
    const float4 v = ((const float4*)src)[i];
    u16x4 o;
    o[0] = f2u(v.x * scale); o[1] = f2u(v.y * scale);
    o[2] = f2u(v.z * scale); o[3] = f2u(v.w * scale);
    ((u16x4*)dst)[i] = o;
  }
}

// ---------------------------------------------------------------------------
// bf16 MFMA GEMM: C[M,N] = A[M,K] @ W[N,K]^T, A/W bf16, C f32 or bf16.
// 128x128 tile, BK=32, 4 waves (2x2 of 64x64), global_load_lds staging,
// XOR-swizzled k-slots (pre-swizzled global source + swizzled ds_read -> the
// data delivered to each fragment is canonical k; banks spread 8-way).
// Grid: (ceil(N/128), M/128). W rows clamped, C cols guarded (N=576 case).
// ---------------------------------------------------------------------------
template <bool BF16_OUT>
__global__ __launch_bounds__(256) void gemm_mfma(const unsigned short* __restrict__ A,
                                                 const unsigned short* __restrict__ W,
                                                 void* __restrict__ Cv,
                                                 int N, int K) {
  __shared__ unsigned short As[128 * 32];
  __shared__ unsigned short Ws[128 * 32];
  const int tid = threadIdx.x;
  const int wave = tid >> 6, lane = tid & 63;
  const int col16 = lane & 15, g = lane >> 4;
  const int arow = blockIdx.y * 128, wrow = blockIdx.x * 128;
  const int wm = (wave >> 1) * 64, wn = (wave & 1) * 64;

  // staging: chunk c in [0,512) -> LDS row c>>2, slot c&3; global k-offset
  // pre-swizzled so LDS slot s of row r holds k-group (s ^ ((r>>1)&3)).
  const int c0 = tid, c1 = 256 + tid;
  const int rA0 = c0 >> 2, rA1 = c1 >> 2;
  const int ko0 = ((c0 & 3) ^ ((rA0 >> 1) & 3)) * 8;
  const int ko1 = ((c1 & 3) ^ ((rA1 >> 1) & 3)) * 8;
  const unsigned short* gA0 = A + (size_t)(arow + rA0) * K + ko0;
  const unsigned short* gA1 = A + (size_t)(arow + rA1) * K + ko1;
  const int wr0 = (wrow + rA0 < N) ? wrow + rA0 : N - 1;
  const int wr1 = (wrow + rA1 < N) ? wrow + rA1 : N - 1;
  const unsigned short* gW0 = W + (size_t)wr0 * K + ko0;
  const unsigned short* gW1 = W + (size_t)wr1 * K + ko1;
  unsigned short* lA0 = As + wave * 512;          // chunks [wave*64, +64)
  unsigned short* lA1 = As + 2048 + wave * 512;   // chunks [256+wave*64, +64)
  unsigned short* lW0 = Ws + wave * 512;
  unsigned short* lW1 = Ws + 2048 + wave * 512;

  f32x4 acc[4][4];
#pragma unroll
  for (int i = 0; i < 4; ++i)
#pragma unroll
    for (int j = 0; j < 4; ++j) acc[i][j] = (f32x4){0.f, 0.f, 0.f, 0.f};

  gload_lds16(gA0, lA0); gload_lds16(gA1, lA1);
  gload_lds16(gW0, lW0); gload_lds16(gW1, lW1);

  for (int k0 = 0;;) {
    __syncthreads();  // drains vmcnt (compiler emits waitcnt before barrier)
    bf16x8 af[4], bf[4];
#pragma unroll
    for (int i = 0; i < 4; ++i) {
      const int row = wm + i * 16 + col16;
      af[i] = *(const bf16x8*)(As + row * 32 + ((g ^ ((row >> 1) & 3)) * 8));
    }
#pragma unroll
    for (int j = 0; j < 4; ++j) {
      const int row = wn + j * 16 + col16;
      bf[j] = *(const bf16x8*)(Ws + row * 32 + ((g ^ ((row >> 1) & 3)) * 8));
    }
#pragma unroll
    for (int i = 0; i < 4; ++i)
#pragma unroll
      for (int j = 0; j < 4; ++j)
        acc[i][j] = __builtin_amdgcn_mfma_f32_16x16x32_bf16(af[i], bf[j], acc[i][j], 0, 0, 0);
    k0 += 32;
    if (k0 >= K) break;
    __syncthreads();  // all waves done reading before re-stage
    gload_lds16(gA0 + k0, lA0); gload_lds16(gA1 + k0, lA1);
    gload_lds16(gW0 + k0, lW0); gload_lds16(gW1 + k0, lW1);
  }

#pragma unroll
  for (int i = 0; i < 4; ++i)
#pragma unroll
    for (int j = 0; j < 4; ++j) {
      const int col = wrow + wn + j * 16 + col16;
      if (col < N) {
        const int row0 = arow + wm + i * 16 + g * 4;
#pragma unroll
        for (int r = 0; r < 4; ++r) {
          if constexpr (BF16_OUT)
            ((unsigned short*)Cv)[(size_t)(row0 + r) * N + col] = f2u(acc[i][j][r]);
          else
            ((float*)Cv)[(size_t)(row0 + r) * N + col] = acc[i][j][r];
        }
      }
    }
}

// ---------------------------------------------------------------------------
// RMSNorm over last dim, f32 in -> bf16 out.
// ---------------------------------------------------------------------------
__global__ __launch_bounds__(256) void rmsnorm_kernel(const float* __restrict__ src, int src_ld,
                                                      const float* __restrict__ w,
                                                      unsigned short* __restrict__ dst, int dst_ld,
                                                      int dim) {
  const int row = blockIdx.x;
  const float* x = src + (size_t)row * src_ld;
  float ss = 0.f;
  for (int i = threadIdx.x; i < dim; i += 256) {
    float v = x[i];
    ss += v * v;
  }
#pragma unroll
  for (int off = 32; off; off >>= 1) ss += __shfl_xor(ss, off);
  __shared__ float red[4];
  const int wv = threadIdx.x >> 6, ln = threadIdx.x & 63;
  if (ln == 0) red[wv] = ss;
  __syncthreads();
  const float tot = red[0] + red[1] + red[2] + red[3];
  const float scale = rsqrtf(tot / (float)dim + 1e-6f);
  for (int i = threadIdx.x; i < dim; i += 256) {
    dst[(size_t)row * dst_ld + i] = f2u(w[i] * (x[i] * scale));
  }
}

// ---------------------------------------------------------------------------
// RoPE: q_pe slices of bf16 qbuf in place; k_pe from f32 ckv -> bf16 kpe.
// ---------------------------------------------------------------------------
__global__ void rope_kernel(unsigned short* __restrict__ q, const float* __restrict__ ckv,
                            unsigned short* __restrict__ kpe, const int* __restrict__ pos_ids) {
  const int s = blockIdx.x;
  const int j = threadIdx.x;  // 0..31
  const float t = (float)pos_ids[s];
  const float invf = powf(50000.0f, -(float)(2 * j) / 64.0f);
  const float ang = t * invf;
  const float c = cosf(ang), sn = sinf(ang);
  for (int h = 0; h < N_HEADS; ++h) {
    unsigned short* base = q + (size_t)s * (N_HEADS * QHD) + h * QHD + NOPE;
    const float x0 = u2f(base[2 * j]), x1 = u2f(base[2 * j + 1]);
    __syncthreads();
    base[j] = f2u(x0 * c - x1 * sn);
    base[32 + j] = f2u(x1 * c + x0 * sn);
    __syncthreads();
  }
  const float* kb = ckv + (size_t)s * (KV_LORA + ROPE_D) + KV_LORA;
  kpe[(size_t)s * ROPE_D + j] = f2u(kb[2 * j] * c - kb[2 * j + 1] * sn);
  kpe[(size_t)s * ROPE_D + 32 + j] = f2u(kb[2 * j + 1] * c + kb[2 * j] * sn);
}

// ---------------------------------------------------------------------------
// V transpose: bf16 kvbuf (S, H*256) value halves -> Vt (H, 128, S)
// ---------------------------------------------------------------------------
__global__ __launch_bounds__(256) void build_vt(const unsigned short* __restrict__ kv,
                                                unsigned short* __restrict__ Vt) {
  __shared__ unsigned short t[32][33];
  const int s0 = blockIdx.x * 32, d0 = blockIdx.y * 32, h = blockIdx.z;
  const int tx = threadIdx.x & 31, ty = threadIdx.x >> 5;
#pragma unroll
  for (int i = 0; i < 4; ++i) {
    const int s = s0 + ty + i * 8;
    t[ty + i * 8][tx] = kv[(size_t)s * (N_HEADS * 256) + h * 256 + NOPE + d0 + tx];
  }
  __syncthreads();
#pragma unroll
  for (int i = 0; i < 4; ++i) {
    const int d = d0 + ty + i * 8;
    Vt[((size_t)h * VD + d) * S_LEN + s0 + tx] = t[tx][ty + i * 8];
  }
}

// ---------------------------------------------------------------------------
// MFMA flash attention (reads qbuf/kvbuf/kpe in place; writes bf16 attn).
// One wave = 16 q rows of one head. Scores swapped: C = mfma(K, Q^T).
// PV: O^T = mfma(V^T, P), identical in-lane k-map on both operands.
// ---------------------------------------------------------------------------
__global__ __launch_bounds__(256) void flash_attn(const unsigned short* __restrict__ Q,   // (S, 3072), pre-scaled
                                                  const unsigned short* __restrict__ KV,  // (S, 4096)
                                                  const unsigned short* __restrict__ KPE, // (S, 64)
                                                  const unsigned short* __restrict__ Vt,  // (H, 128, S)
                                                  unsigned short* __restrict__ out) {     // (S, 2048)
  const int wave = threadIdx.x >> 6, lane = threadIdx.x & 63;
  const int g = lane >> 4, col = lane & 15;
  const int h = blockIdx.y;
  const int qtile = (int)(gridDim.x - 1 - blockIdx.x);  // heavy blocks first
  const int qw = qtile * 64 + wave * 16;
  const int qr = qw + col;

  bf16x8 qf[6];
  {
    const unsigned short* qrow = Q + (size_t)(qw + col) * (N_HEADS * QHD) + h * QHD + g * 8;
#pragma unroll
    for (int t = 0; t < 6; ++t) qf[t] = *(const bf16x8*)(qrow + t * 32);
  }
  f32x4 o[8];
#pragma unroll
  for (int i = 0; i < 8; ++i) o[i] = (f32x4){0.f, 0.f, 0.f, 0.f};
  float m = -1e30f, l = 0.f;

  const unsigned short* vbase = Vt + (size_t)h * VD * S_LEN;
  const int nblk = (qw + 16 + 31) >> 5;

  for (int kb = 0; kb < nblk; ++kb) {
    const int k0 = kb * 32;
    f32x4 c0 = (f32x4){0.f, 0.f, 0.f, 0.f}, c1 = (f32x4){0.f, 0.f, 0.f, 0.f};
    const unsigned short* ka0 = KV + (size_t)(k0 + col) * (N_HEADS * 256) + h * 256 + g * 8;
    const unsigned short* ka1 = ka0 + (size_t)16 * (N_HEADS * 256);
    const unsigned short* pe0 = KPE + (size_t)(k0 + col) * ROPE_D + g * 8;
    const unsigned short* pe1 = pe0 + 16 * ROPE_D;
#pragma unroll
    for (int t = 0; t < 4; ++t) {
      bf16x8 a0 = *(const bf16x8*)(ka0 + t * 32);
      bf16x8 a1 = *(const bf16x8*)(ka1 + t * 32);
      c0 = __builtin_amdgcn_mfma_f32_16x16x32_bf16(a0, qf[t], c0, 0, 0, 0);
      c1 = __builtin_amdgcn_mfma_f32_16x16x32_bf16(a1, qf[t], c1, 0, 0, 0);
    }
#pragma unroll
    for (int t = 4; t < 6; ++t) {
      bf16x8 a0 = *(const bf16x8*)(pe0 + (t - 4) * 32);
      bf16x8 a1 = *(const bf16x8*)(pe1 + (t - 4) * 32);
      c0 = __builtin_amdgcn_mfma_f32_16x16x32_bf16(a0, qf[t], c0, 0, 0, 0);
      c1 = __builtin_amdgcn_mfma_f32_16x16x32_bf16(a1, qf[t], c1, 0, 0, 0);
    }
    // causal mask + online softmax (q = lane&15; k = k0 + 16*frag + 4g + r)
    float s0[4], s1[4];
#pragma unroll
    for (int r = 0; r < 4; ++r) {
      const int kk = k0 + 4 * g + r;
      s0[r] = (kk <= qr) ? c0[r] : -1e30f;
      s1[r] = (kk + 16 <= qr) ? c1[r] : -1e30f;
    }
    float bm = fmaxf(fmaxf(fmaxf(s0[0], s0[1]), fmaxf(s0[2], s0[3])),
                     fmaxf(fmaxf(s1[0], s1[1]), fmaxf(s1[2], s1[3])));
    bm = fmaxf(bm, __shfl_xor(bm, 16));
    bm = fmaxf(bm, __shfl_xor(bm, 32));
    const float mn = fmaxf(m, bm);
    const float corr = __expf(m - mn);
    float ps = 0.f;
    bf16x8 pb;
#pragma unroll
    for (int r = 0; r < 4; ++r) {
      const float p0 = __expf(s0[r] - mn);
      const float p1 = __expf(s1[r] - mn);
      ps += p0 + p1;
      pb[r] = (short)f2u(p0);
      pb[4 + r] = (short)f2u(p1);
    }
    ps += __shfl_xor(ps, 16);
    ps += __shfl_xor(ps, 32);
    l = l * corr + ps;
    m = mn;
#pragma unroll
    for (int i = 0; i < 8; ++i) {
      o[i][0] *= corr; o[i][1] *= corr; o[i][2] *= corr; o[i][3] *= corr;
    }
#pragma unroll
    for (int db = 0; db < 8; ++db) {
      const unsigned short* vrow = vbase + (size_t)(db * 16 + col) * S_LEN + k0 + 4 * g;
      V8 tmp;
      tmp.lo = *(const uint2*)(vrow);
      tmp.hi = *(const uint2*)(vrow + 16);
      const bf16x8 va = __builtin_bit_cast(bf16x8, tmp);
      o[db] = __builtin_amdgcn_mfma_f32_16x16x32_bf16(va, pb, o[db], 0, 0, 0);
    }
  }
  const float inv = 1.f / l;
  unsigned short* orow = out + (size_t)(qw + col) * (N_HEADS * VD) + h * VD;
#pragma unroll
  for (int db = 0; db < 8; ++db)
#pragma unroll
    for (int r = 0; r < 4; ++r)
      orow[db * 16 + 4 * g + r] = f2u(o[db][r] * inv);
}

// ---------------------------------------------------------------------------
extern "C" void kernel_launch(void* const* d_in, const int* in_sizes, int n_in,
                              void* d_out, int out_size, void* d_ws, size_t ws_size,
                              hipStream_t stream) {
  const float* hidden    = (const float*)d_in[0];
  const int*   pos       = (const int*)d_in[1];
  const float* q_a_w     = (const float*)d_in[2];
  const float* q_a_ln_w  = (const float*)d_in[3];
  const float* q_b_w     = (const float*)d_in[4];
  const float* kv_a_w    = (const float*)d_in[5];
  const float* kv_a_ln_w = (const float*)d_in[6];
  const float* kv_b_w    = (const float*)d_in[7];
  const float* o_w       = (const float*)d_in[8];
  float* out = (float*)d_out;
  (void)in_sizes; (void)n_in; (void)out_size; (void)ws_size;

  // workspace layout (bytes, 256-aligned); total ~73 MB
  char* base = (char*)d_ws;
  unsigned short* qbuf  = (unsigned short*)(base);              // S*3072 bf16 = 12.58MB
  unsigned short* kvbuf = (unsigned short*)(base + 12582912);   // S*4096 bf16 = 16.78MB
  float*          ckv   = (float*)(base + 29360128);            // S*576 f32   =  4.72MB
  float*          qa    = (float*)(base + 34078720);            // S*1536 f32  = 12.58MB
  unsigned short* attnb = (unsigned short*)(base + 34078720);   //   overlay: S*2048 bf16 (qa dead)
  unsigned short* qan   = (unsigned short*)(base + 46661632);   // S*1536 bf16 =  6.29MB
  unsigned short* ckvn  = (unsigned short*)(base + 52953088);   // S*512 bf16  =  2.10MB
  unsigned short* Hb    = (unsigned short*)(base + 55050240);   // S*2048 bf16 =  8.39MB
  unsigned short* Vt    = (unsigned short*)(base + 55050240);   //   overlay: 16*128*S bf16 (Hb dead)
  unsigned short* wbuf  = (unsigned short*)(base + 63438848);   // 4.72M bf16  =  9.44MB
  unsigned short* kpe   = (unsigned short*)(base + 72876032);   // S*64 bf16   =  0.26MB

  const dim3 b256(256);
  const float qscale = 0.07216878364870323f;  // 192^-0.5, folded into q_b_w

  // hidden -> bf16
  conv_bf16<<<2048, b256, 0, stream>>>(hidden, Hb, (S_LEN * D_MODEL) / 4, 1.f);

  // q_a = Hb @ q_a_w^T   (f32 out)
  conv_bf16<<<2048, b256, 0, stream>>>(q_a_w, wbuf, (Q_LORA * D_MODEL) / 4, 1.f);
  gemm_mfma<false><<<dim3(Q_LORA / 128, S_LEN / 128), b256, 0, stream>>>(Hb, wbuf, qa, Q_LORA, D_MODEL);
  rmsnorm_kernel<<<S_LEN, b256, 0, stream>>>(qa, Q_LORA, q_a_ln_w, qan, Q_LORA, Q_LORA);

  // qbuf = qan @ (scale*q_b_w)^T   (bf16 out)
  conv_bf16<<<2048, b256, 0, stream>>>(q_b_w, wbuf, (N_HEADS * QHD * Q_LORA) / 4, qscale);
  gemm_mfma<true><<<dim3(N_HEADS * QHD / 128, S_LEN / 128), b256, 0, stream>>>(qan, wbuf, qbuf, N_HEADS * QHD, Q_LORA);

  // ckv = Hb @ kv_a_w^T   (f32 out, N=576 -> 5 tiles with guard)
  conv_bf16<<<2048, b256, 0, stream>>>(kv_a_w, wbuf, ((KV_LORA + ROPE_D) * D_MODEL) / 4, 1.f);
  gemm_mfma<false><<<dim3(5, S_LEN / 128), b256, 0, stream>>>(Hb, wbuf, ckv, KV_LORA + ROPE_D, D_MODEL);
  rmsnorm_kernel<<<S_LEN, b256, 0, stream>>>(ckv, KV_LORA + ROPE_D, kv_a_ln_w, ckvn, KV_LORA, KV_LORA);

  // rope: qbuf q_pe in place (bf16), ckv k_pe -> kpe bf16
  rope_kernel<<<S_LEN, 32, 0, stream>>>(qbuf, ckv, kpe, pos);

  // kvbuf = ckvn @ kv_b_w^T   (bf16 out)
  conv_bf16<<<2048, b256, 0, stream>>>(kv_b_w, wbuf, (N_HEADS * 256 * KV_LORA) / 4, 1.f);
  gemm_mfma<true><<<dim3(N_HEADS * 256 / 128, S_LEN / 128), b256, 0, stream>>>(ckvn, wbuf, kvbuf, N_HEADS * 256, KV_LORA);

  // V transpose + attention
  build_vt<<<dim3(S_LEN / 32, VD / 32, N_HEADS), b256, 0, stream>>>(kvbuf, Vt);
  flash_attn<<<dim3(S_LEN / 64, N_HEADS), b256, 0, stream>>>(qbuf, kvbuf, kpe, Vt, attnb);

  // out = attnb @ o_w^T   (f32 out)
  conv_bf16<<<2048, b256, 0, stream>>>(o_w, wbuf, (D_MODEL * N_HEADS * VD) / 4, 1.f);
  gemm_mfma<false><<<dim3(D_MODEL / 128, S_LEN / 128), b256, 0, stream>>>(attnb, wbuf, out, D_MODEL, N_HEADS * VD);
}

// Round 4
// 333.282 us; speedup vs baseline: 13.7044x; 1.7925x over previous
//
#include <hip/hip_runtime.h>
#include <hip/hip_bf16.h>
#include <cmath>

#define S_LEN 2048
#define D_MODEL 2048
#define N_HEADS 16
#define Q_LORA 1536
#define KV_LORA 512
#define NOPE 128
#define ROPE_D 64
#define VD 128
#define QHD 192

typedef __attribute__((ext_vector_type(8))) short bf16x8;
typedef __attribute__((ext_vector_type(4))) float f32x4;
typedef __attribute__((ext_vector_type(4))) unsigned short u16x4;

struct V8 { uint2 lo, hi; };

static __device__ __forceinline__ unsigned short f2u(float x) {
  union { float f; unsigned u; } v; v.f = x;
  unsigned r = v.u + 0x7fffu + ((v.u >> 16) & 1u);  // RNE
  return (unsigned short)(r >> 16);
}
static __device__ __forceinline__ float u2f(unsigned short x) {
  union { unsigned u; float f; } v; v.u = ((unsigned)x) << 16;
  return v.f;
}

#define AS1 __attribute__((address_space(1)))
#define AS3 __attribute__((address_space(3)))
static __device__ __forceinline__ void gload_lds16(const unsigned short* g, unsigned short* l) {
  __builtin_amdgcn_global_load_lds((const AS1 unsigned int*)g, (AS3 unsigned int*)l, 16, 0, 0);
}

// ---------------------------------------------------------------------------
// f32 -> bf16 convert (optionally scaled). n4 = elements/4.
// ---------------------------------------------------------------------------
__global__ __launch_bounds__(256) void conv_bf16(const float* __restrict__ src,
                                                 unsigned short* __restrict__ dst,
                                                 int n4, float scale) {
  for (int i = blockIdx.x * 256 + threadIdx.x; i < n4; i += gridDim.x * 256) {
    const float4 v = ((const float4*)src)[i];
    u16x4 o;
    o[0] = f2u(v.x * scale); o[1] = f2u(v.y * scale);
    o[2] = f2u(v.z * scale); o[3] = f2u(v.w * scale);
    ((u16x4*)dst)[i] = o;
  }
}

// ---------------------------------------------------------------------------
// bf16 MFMA GEMM: C[M,N] = A[M,K] @ W[N,K]^T  (unchanged from round 3)
// ---------------------------------------------------------------------------
template <bool BF16_OUT>
__global__ __launch_bounds__(256) void gemm_mfma(const unsigned short* __restrict__ A,
                                                 const unsigned short* __restrict__ W,
                                                 void* __restrict__ Cv,
                                                 int N, int K) {
  __shared__ unsigned short As[128 * 32];
  __shared__ unsigned short Ws[128 * 32];
  const int tid = threadIdx.x;
  const int wave = tid >> 6, lane = tid & 63;
  const int col16 = lane & 15, g = lane >> 4;
  const int arow = blockIdx.y * 128, wrow = blockIdx.x * 128;
  const int wm = (wave >> 1) * 64, wn = (wave & 1) * 64;

  const int c0 = tid, c1 = 256 + tid;
  const int rA0 = c0 >> 2, rA1 = c1 >> 2;
  const int ko0 = ((c0 & 3) ^ ((rA0 >> 1) & 3)) * 8;
  const int ko1 = ((c1 & 3) ^ ((rA1 >> 1) & 3)) * 8;
  const unsigned short* gA0 = A + (size_t)(arow + rA0) * K + ko0;
  const unsigned short* gA1 = A + (size_t)(arow + rA1) * K + ko1;
  const int wr0 = (wrow + rA0 < N) ? wrow + rA0 : N - 1;
  const int wr1 = (wrow + rA1 < N) ? wrow + rA1 : N - 1;
  const unsigned short* gW0 = W + (size_t)wr0 * K + ko0;
  const unsigned short* gW1 = W + (size_t)wr1 * K + ko1;
  unsigned short* lA0 = As + wave * 512;
  unsigned short* lA1 = As + 2048 + wave * 512;
  unsigned short* lW0 = Ws + wave * 512;
  unsigned short* lW1 = Ws + 2048 + wave * 512;

  f32x4 acc[4][4];
#pragma unroll
  for (int i = 0; i < 4; ++i)
#pragma unroll
    for (int j = 0; j < 4; ++j) acc[i][j] = (f32x4){0.f, 0.f, 0.f, 0.f};

  gload_lds16(gA0, lA0); gload_lds16(gA1, lA1);
  gload_lds16(gW0, lW0); gload_lds16(gW1, lW1);

  for (int k0 = 0;;) {
    __syncthreads();
    bf16x8 af[4], bf[4];
#pragma unroll
    for (int i = 0; i < 4; ++i) {
      const int row = wm + i * 16 + col16;
      af[i] = *(const bf16x8*)(As + row * 32 + ((g ^ ((row >> 1) & 3)) * 8));
    }
#pragma unroll
    for (int j = 0; j < 4; ++j) {
      const int row = wn + j * 16 + col16;
      bf[j] = *(const bf16x8*)(Ws + row * 32 + ((g ^ ((row >> 1) & 3)) * 8));
    }
#pragma unroll
    for (int i = 0; i < 4; ++i)
#pragma unroll
      for (int j = 0; j < 4; ++j)
        acc[i][j] = __builtin_amdgcn_mfma_f32_16x16x32_bf16(af[i], bf[j], acc[i][j], 0, 0, 0);
    k0 += 32;
    if (k0 >= K) break;
    __syncthreads();
    gload_lds16(gA0 + k0, lA0); gload_lds16(gA1 + k0, lA1);
    gload_lds16(gW0 + k0, lW0); gload_lds16(gW1 + k0, lW1);
  }

#pragma unroll
  for (int i = 0; i < 4; ++i)
#pragma unroll
    for (int j = 0; j < 4; ++j) {
      const int col = wrow + wn + j * 16 + col16;
      if (col < N) {
        const int row0 = arow + wm + i * 16 + g * 4;
#pragma unroll
        for (int r = 0; r < 4; ++r) {
          if constexpr (BF16_OUT)
            ((unsigned short*)Cv)[(size_t)(row0 + r) * N + col] = f2u(acc[i][j][r]);
          else
            ((float*)Cv)[(size_t)(row0 + r) * N + col] = acc[i][j][r];
        }
      }
    }
}

// ---------------------------------------------------------------------------
// RMSNorm over last dim, f32 in -> bf16 out. (unchanged)
// ---------------------------------------------------------------------------
__global__ __launch_bounds__(256) void rmsnorm_kernel(const float* __restrict__ src, int src_ld,
                                                      const float* __restrict__ w,
                                                      unsigned short* __restrict__ dst, int dst_ld,
                                                      int dim) {
  const int row = blockIdx.x;
  const float* x = src + (size_t)row * src_ld;
  float ss = 0.f;
  for (int i = threadIdx.x; i < dim; i += 256) {
    float v = x[i];
    ss += v * v;
  }
#pragma unroll
  for (int off = 32; off; off >>= 1) ss += __shfl_xor(ss, off);
  __shared__ float red[4];
  const int wv = threadIdx.x >> 6, ln = threadIdx.x & 63;
  if (ln == 0) red[wv] = ss;
  __syncthreads();
  const float tot = red[0] + red[1] + red[2] + red[3];
  const float scale = rsqrtf(tot / (float)dim + 1e-6f);
  for (int i = threadIdx.x; i < dim; i += 256) {
    dst[(size_t)row * dst_ld + i] = f2u(w[i] * (x[i] * scale));
  }
}

// ---------------------------------------------------------------------------
// RoPE (unchanged)
// ---------------------------------------------------------------------------
__global__ void rope_kernel(unsigned short* __restrict__ q, const float* __restrict__ ckv,
                            unsigned short* __restrict__ kpe, const int* __restrict__ pos_ids) {
  const int s = blockIdx.x;
  const int j = threadIdx.x;  // 0..31
  const float t = (float)pos_ids[s];
  const float invf = powf(50000.0f, -(float)(2 * j) / 64.0f);
  const float ang = t * invf;
  const float c = cosf(ang), sn = sinf(ang);
  for (int h = 0; h < N_HEADS; ++h) {
    unsigned short* base = q + (size_t)s * (N_HEADS * QHD) + h * QHD + NOPE;
    const float x0 = u2f(base[2 * j]), x1 = u2f(base[2 * j + 1]);
    __syncthreads();
    base[j] = f2u(x0 * c - x1 * sn);
    base[32 + j] = f2u(x1 * c + x0 * sn);
    __syncthreads();
  }
  const float* kb = ckv + (size_t)s * (KV_LORA + ROPE_D) + KV_LORA;
  kpe[(size_t)s * ROPE_D + j] = f2u(kb[2 * j] * c - kb[2 * j + 1] * sn);
  kpe[(size_t)s * ROPE_D + 32 + j] = f2u(kb[2 * j + 1] * c + kb[2 * j] * sn);
}

// ---------------------------------------------------------------------------
// V transpose: bf16 kvbuf (S, H*256) value halves -> Vt (H, 128, S)
// ---------------------------------------------------------------------------
__global__ __launch_bounds__(256) void build_vt(const unsigned short* __restrict__ kv,
                                                unsigned short* __restrict__ Vt) {
  __shared__ unsigned short t[32][33];
  const int s0 = blockIdx.x * 32, d0 = blockIdx.y * 32, h = blockIdx.z;
  const int tx = threadIdx.x & 31, ty = threadIdx.x >> 5;
#pragma unroll
  for (int i = 0; i < 4; ++i) {
    const int s = s0 + ty + i * 8;
    t[ty + i * 8][tx] = kv[(size_t)s * (N_HEADS * 256) + h * 256 + NOPE + d0 + tx];
  }
  __syncthreads();
#pragma unroll
  for (int i = 0; i < 4; ++i) {
    const int d = d0 + ty + i * 8;
    Vt[((size_t)h * VD + d) * S_LEN + s0 + tx] = t[tx][ty + i * 8];
  }
}

// ---------------------------------------------------------------------------
// K pack: Kb(h, s, 0:192) = [kvbuf k_nope | kpe]. 16-B chunks, vectorized.
// chunk c -> (h*2048+s) = c/24, slot = c%24.
// ---------------------------------------------------------------------------
__global__ __launch_bounds__(256) void build_k(const unsigned short* __restrict__ kv,
                                               const unsigned short* __restrict__ kpe,
                                               unsigned short* __restrict__ Kb) {
  const int c = blockIdx.x * 256 + threadIdx.x;  // 786432 chunks
  const int sh = c / 24, slot = c - sh * 24;
  const int h = sh >> 11, s = sh & 2047;
  const unsigned short* src = (slot < 16)
      ? kv + (size_t)s * (N_HEADS * 256) + h * 256 + slot * 8
      : kpe + (size_t)s * ROPE_D + (slot - 16) * 8;
  *(uint4*)(Kb + (size_t)c * 8) = *(const uint4*)src;
}

// ---------------------------------------------------------------------------
// MFMA flash attention with LDS-staged, double-buffered K/V shared by all
// 4 waves of the block (each wave owns 16 q rows of the block's 64).
// LDS layout XOR-swizzled via pre-swizzled GLOBAL source offsets (linear LDS
// dest for global_load_lds) + the same XOR on the ds_read side -> canonical
// data, conflict-free banks.
// Scores swapped: C = mfma(K, Q^T) -> q = lane&15. PV: O^T = mfma(V^T, P),
// identical in-lane k-map on both operands.
// ---------------------------------------------------------------------------
__global__ __launch_bounds__(256) void flash_attn(const unsigned short* __restrict__ Q,   // (S,3072) pre-scaled
                                                  const unsigned short* __restrict__ Kb,  // (H,S,192)
                                                  const unsigned short* __restrict__ Vt,  // (H,128,S)
                                                  unsigned short* __restrict__ out) {     // (S,2048)
  __shared__ unsigned short Ks[2][32 * QHD];   // 2 x 12 KB
  __shared__ unsigned short Vs[2][VD * 32];    // 2 x  8 KB
  const int wave = threadIdx.x >> 6, lane = threadIdx.x & 63;
  const int g = lane >> 4, col = lane & 15;
  const int h = blockIdx.y;
  const int qtile = (int)(gridDim.x - 1 - blockIdx.x);  // heavy blocks first
  const int qw = qtile * 64 + wave * 16;
  const int qr = qw + col;

  bf16x8 qf[6];
  {
    const unsigned short* qrow = Q + (size_t)(qw + col) * (N_HEADS * QHD) + h * QHD + g * 8;
#pragma unroll
    for (int t = 0; t < 6; ++t) qf[t] = *(const bf16x8*)(qrow + t * 32);
  }

  const unsigned short* KbH = Kb + (size_t)h * S_LEN * QHD;
  const unsigned short* VtH = Vt + (size_t)h * VD * S_LEN;

  // per-lane staging source offsets (swizzled slot; fixed across k-blocks)
  int eK[3], eV[2];
#pragma unroll
  for (int i = 0; i < 3; ++i) {
    const int c = wave * 64 + i * 256 + lane;     // 768 K chunks of 16 B
    const int r = c / 24, sl = c - r * 24;
    const int sl2 = (sl & 24) | ((sl & 7) ^ (r & 7));
    eK[i] = r * QHD + sl2 * 8;
  }
#pragma unroll
  for (int i = 0; i < 2; ++i) {
    const int c = wave * 64 + i * 256 + lane;     // 512 V chunks of 16 B
    const int r = c >> 2, sl = c & 3;
    eV[i] = r * S_LEN + (sl ^ (r & 3)) * 8;
  }

  f32x4 o[8];
#pragma unroll
  for (int i = 0; i < 8; ++i) o[i] = (f32x4){0.f, 0.f, 0.f, 0.f};
  float m = -1e30f, l = 0.f;

  const int nblkB = 2 * qtile + 2;  // uniform across block (barriers)

  // prologue: stage k-block 0 into buffer 0
#pragma unroll
  for (int i = 0; i < 3; ++i) gload_lds16(KbH + eK[i], &Ks[0][(wave * 64 + i * 256) * 8]);
#pragma unroll
  for (int i = 0; i < 2; ++i) gload_lds16(VtH + eV[i], &Vs[0][(wave * 64 + i * 256) * 8]);

  // ds_read swizzled offsets
  int xK[6];
#pragma unroll
  for (int t = 0; t < 6; ++t) xK[t] = ((4 * t + g) ^ (col & 7)) * 8;
  const int v0o = (((g >> 1) ^ (col & 3)) * 8) + (g & 1) * 4;
  const int v1o = ((((g >> 1) + 2) ^ (col & 3)) * 8) + (g & 1) * 4;

  for (int kb = 0; kb < nblkB; ++kb) {
    __syncthreads();  // buf[kb&1] staged & prior reads of buf[(kb+1)&1] done
    if (kb + 1 < nblkB) {
      const unsigned short* kp = KbH + (size_t)(kb + 1) * 32 * QHD;
      const unsigned short* vp = VtH + (kb + 1) * 32;
      const int b = (kb + 1) & 1;
#pragma unroll
      for (int i = 0; i < 3; ++i) gload_lds16(kp + eK[i], &Ks[b][(wave * 64 + i * 256) * 8]);
#pragma unroll
      for (int i = 0; i < 2; ++i) gload_lds16(vp + eV[i], &Vs[b][(wave * 64 + i * 256) * 8]);
    }
    const int k0 = kb * 32;
    if (k0 <= qw + 15) {
      const unsigned short* Ksc = Ks[kb & 1];
      const unsigned short* Vsc = Vs[kb & 1];
      f32x4 c0 = (f32x4){0.f, 0.f, 0.f, 0.f}, c1 = (f32x4){0.f, 0.f, 0.f, 0.f};
      const int rb = col * QHD;
#pragma unroll
      for (int t = 0; t < 6; ++t) {
        bf16x8 a0 = *(const bf16x8*)(Ksc + rb + xK[t]);
        bf16x8 a1 = *(const bf16x8*)(Ksc + rb + 16 * QHD + xK[t]);
        c0 = __builtin_amdgcn_mfma_f32_16x16x32_bf16(a0, qf[t], c0, 0, 0, 0);
        c1 = __builtin_amdgcn_mfma_f32_16x16x32_bf16(a1, qf[t], c1, 0, 0, 0);
      }
      // causal mask + online softmax (q = lane&15; k = k0 + 16*frag + 4g + r)
      float s0[4], s1[4];
#pragma unroll
      for (int r = 0; r < 4; ++r) {
        const int kk = k0 + 4 * g + r;
        s0[r] = (kk <= qr) ? c0[r] : -1e30f;
        s1[r] = (kk + 16 <= qr) ? c1[r] : -1e30f;
      }
      float bm = fmaxf(fmaxf(fmaxf(s0[0], s0[1]), fmaxf(s0[2], s0[3])),
                       fmaxf(fmaxf(s1[0], s1[1]), fmaxf(s1[2], s1[3])));
      bm = fmaxf(bm, __shfl_xor(bm, 16));
      bm = fmaxf(bm, __shfl_xor(bm, 32));
      const float mn = fmaxf(m, bm);
      const float corr = __expf(m - mn);
      float ps = 0.f;
      bf16x8 pb;
#pragma unroll
      for (int r = 0; r < 4; ++r) {
        const float p0 = __expf(s0[r] - mn);
        const float p1 = __expf(s1[r] - mn);
        ps += p0 + p1;
        pb[r] = (short)f2u(p0);
        pb[4 + r] = (short)f2u(p1);
      }
      ps += __shfl_xor(ps, 16);
      ps += __shfl_xor(ps, 32);
      l = l * corr + ps;
      m = mn;
#pragma unroll
      for (int i = 0; i < 8; ++i) {
        o[i][0] *= corr; o[i][1] *= corr; o[i][2] *= corr; o[i][3] *= corr;
      }
#pragma unroll
      for (int db = 0; db < 8; ++db) {
        const unsigned short* vr = Vsc + (db * 16 + col) * 32;
        V8 tmp;
        tmp.lo = *(const uint2*)(vr + v0o);
        tmp.hi = *(const uint2*)(vr + v1o);
        const bf16x8 va = __builtin_bit_cast(bf16x8, tmp);
        o[db] = __builtin_amdgcn_mfma_f32_16x16x32_bf16(va, pb, o[db], 0, 0, 0);
      }
    }
  }
  const float inv = 1.f / l;
  unsigned short* orow = out + (size_t)(qw + col) * (N_HEADS * VD) + h * VD;
#pragma unroll
  for (int db = 0; db < 8; ++db)
#pragma unroll
    for (int r = 0; r < 4; ++r)
      orow[db * 16 + 4 * g + r] = f2u(o[db][r] * inv);
}

// ---------------------------------------------------------------------------
extern "C" void kernel_launch(void* const* d_in, const int* in_sizes, int n_in,
                              void* d_out, int out_size, void* d_ws, size_t ws_size,
                              hipStream_t stream) {
  const float* hidden    = (const float*)d_in[0];
  const int*   pos       = (const int*)d_in[1];
  const float* q_a_w     = (const float*)d_in[2];
  const float* q_a_ln_w  = (const float*)d_in[3];
  const float* q_b_w     = (const float*)d_in[4];
  const float* kv_a_w    = (const float*)d_in[5];
  const float* kv_a_ln_w = (const float*)d_in[6];
  const float* kv_b_w    = (const float*)d_in[7];
  const float* o_w       = (const float*)d_in[8];
  float* out = (float*)d_out;
  (void)in_sizes; (void)n_in; (void)out_size; (void)ws_size;

  // workspace layout (bytes, 256-aligned); total ~86 MB
  char* base = (char*)d_ws;
  unsigned short* qbuf  = (unsigned short*)(base);              // S*3072 bf16
  unsigned short* kvbuf = (unsigned short*)(base + 12582912);   // S*4096 bf16
  float*          ckv   = (float*)(base + 29360128);            // S*576 f32
  float*          qa    = (float*)(base + 34078720);            // S*1536 f32
  unsigned short* attnb = (unsigned short*)(base + 34078720);   //   overlay (qa dead)
  unsigned short* qan   = (unsigned short*)(base + 46661632);   // S*1536 bf16
  unsigned short* ckvn  = (unsigned short*)(base + 52953088);   // S*512 bf16
  unsigned short* Hb    = (unsigned short*)(base + 55050240);   // S*2048 bf16
  unsigned short* Vt    = (unsigned short*)(base + 55050240);   //   overlay (Hb dead)
  unsigned short* wbuf  = (unsigned short*)(base + 63438848);   // 4.72M bf16
  unsigned short* kpe   = (unsigned short*)(base + 72876032);   // S*64 bf16
  unsigned short* Kb    = (unsigned short*)(base + 73400320);   // 16*S*192 bf16 = 12.58MB

  const dim3 b256(256);
  const float qscale = 0.07216878364870323f;  // 192^-0.5, folded into q_b_w

  conv_bf16<<<2048, b256, 0, stream>>>(hidden, Hb, (S_LEN * D_MODEL) / 4, 1.f);

  conv_bf16<<<2048, b256, 0, stream>>>(q_a_w, wbuf, (Q_LORA * D_MODEL) / 4, 1.f);
  gemm_mfma<false><<<dim3(Q_LORA / 128, S_LEN / 128), b256, 0, stream>>>(Hb, wbuf, qa, Q_LORA, D_MODEL);
  rmsnorm_kernel<<<S_LEN, b256, 0, stream>>>(qa, Q_LORA, q_a_ln_w, qan, Q_LORA, Q_LORA);

  conv_bf16<<<2048, b256, 0, stream>>>(q_b_w, wbuf, (N_HEADS * QHD * Q_LORA) / 4, qscale);
  gemm_mfma<true><<<dim3(N_HEADS * QHD / 128, S_LEN / 128), b256, 0, stream>>>(qan, wbuf, qbuf, N_HEADS * QHD, Q_LORA);

  conv_bf16<<<2048, b256, 0, stream>>>(kv_a_w, wbuf, ((KV_LORA + ROPE_D) * D_MODEL) / 4, 1.f);
  gemm_mfma<false><<<dim3(5, S_LEN / 128), b256, 0, stream>>>(Hb, wbuf, ckv, KV_LORA + ROPE_D, D_MODEL);
  rmsnorm_kernel<<<S_LEN, b256, 0, stream>>>(ckv, KV_LORA + ROPE_D, kv_a_ln_w, ckvn, KV_LORA, KV_LORA);

  rope_kernel<<<S_LEN, 32, 0, stream>>>(qbuf, ckv, kpe, pos);

  conv_bf16<<<2048, b256, 0, stream>>>(kv_b_w, wbuf, (N_HEADS * 256 * KV_LORA) / 4, 1.f);
  gemm_mfma<true><<<dim3(N_HEADS * 256 / 128, S_LEN / 128), b256, 0, stream>>>(ckvn, wbuf, kvbuf, N_HEADS * 256, KV_LORA);

  build_vt<<<dim3(S_LEN / 32, VD / 32, N_HEADS), b256, 0, stream>>>(kvbuf, Vt);
  build_k<<<3072, b256, 0, stream>>>(kvbuf, kpe, Kb);
  flash_attn<<<dim3(S_LEN / 64, N_HEADS), b256, 0, stream>>>(qbuf, Kb, Vt, attnb);

  conv_bf16<<<2048, b256, 0, stream>>>(o_w, wbuf, (D_MODEL * N_HEADS * VD) / 4, 1.f);
  gemm_mfma<false><<<dim3(D_MODEL / 128, S_LEN / 128), b256, 0, stream>>>(attnb, wbuf, out, D_MODEL, N_HEADS * VD);
}

// Round 5
// 279.596 us; speedup vs baseline: 16.3359x; 1.1920x over previous
//
#include <hip/hip_runtime.h>
#include <hip/hip_bf16.h>
#include <cmath>

#define S_LEN 2048
#define D_MODEL 2048
#define N_HEADS 16
#define Q_LORA 1536
#define KV_LORA 512
#define NOPE 128
#define ROPE_D 64
#define VD 128
#define QHD 192

typedef __attribute__((ext_vector_type(8))) short bf16x8;
typedef __attribute__((ext_vector_type(4))) float f32x4;
typedef __attribute__((ext_vector_type(4))) unsigned short u16x4;

static __device__ __forceinline__ unsigned short f2u(float x) {
  union { float f; unsigned u; } v; v.f = x;
  unsigned r = v.u + 0x7fffu + ((v.u >> 16) & 1u);  // RNE
  return (unsigned short)(r >> 16);
}
static __device__ __forceinline__ float u2f(unsigned short x) {
  union { unsigned u; float f; } v; v.u = ((unsigned)x) << 16;
  return v.f;
}

#define AS1 __attribute__((address_space(1)))
#define AS3 __attribute__((address_space(3)))
static __device__ __forceinline__ void gload_lds16(const unsigned short* g, unsigned short* l) {
  __builtin_amdgcn_global_load_lds((const AS1 unsigned int*)g, (AS3 unsigned int*)l, 16, 0, 0);
}

// ---------------------------------------------------------------------------
// f32 -> bf16 convert (optionally scaled). n4 = elements/4.
// ---------------------------------------------------------------------------
__global__ __launch_bounds__(256) void conv_bf16(const float* __restrict__ src,
                                                 unsigned short* __restrict__ dst,
                                                 int n4, float scale) {
  for (int i = blockIdx.x * 256 + threadIdx.x; i < n4; i += gridDim.x * 256) {
    const float4 v = ((const float4*)src)[i];
    u16x4 o;
    o[0] = f2u(v.x * scale); o[1] = f2u(v.y * scale);
    o[2] = f2u(v.z * scale); o[3] = f2u(v.w * scale);
    ((u16x4*)dst)[i] = o;
  }
}

// ---------------------------------------------------------------------------
// bf16 MFMA GEMM: C[M,N] = A[M,K] @ W[N,K]^T  (unchanged from round 4)
// ---------------------------------------------------------------------------
template <bool BF16_OUT>
__global__ __launch_bounds__(256) void gemm_mfma(const unsigned short* __restrict__ A,
                                                 const unsigned short* __restrict__ W,
                                                 void* __restrict__ Cv,
                                                 int N, int K) {
  __shared__ unsigned short As[128 * 32];
  __shared__ unsigned short Ws[128 * 32];
  const int tid = threadIdx.x;
  const int wave = tid >> 6, lane = tid & 63;
  const int col16 = lane & 15, g = lane >> 4;
  const int arow = blockIdx.y * 128, wrow = blockIdx.x * 128;
  const int wm = (wave >> 1) * 64, wn = (wave & 1) * 64;

  const int c0 = tid, c1 = 256 + tid;
  const int rA0 = c0 >> 2, rA1 = c1 >> 2;
  const int ko0 = ((c0 & 3) ^ ((rA0 >> 1) & 3)) * 8;
  const int ko1 = ((c1 & 3) ^ ((rA1 >> 1) & 3)) * 8;
  const unsigned short* gA0 = A + (size_t)(arow + rA0) * K + ko0;
  const unsigned short* gA1 = A + (size_t)(arow + rA1) * K + ko1;
  const int wr0 = (wrow + rA0 < N) ? wrow + rA0 : N - 1;
  const int wr1 = (wrow + rA1 < N) ? wrow + rA1 : N - 1;
  const unsigned short* gW0 = W + (size_t)wr0 * K + ko0;
  const unsigned short* gW1 = W + (size_t)wr1 * K + ko1;
  unsigned short* lA0 = As + wave * 512;
  unsigned short* lA1 = As + 2048 + wave * 512;
  unsigned short* lW0 = Ws + wave * 512;
  unsigned short* lW1 = Ws + 2048 + wave * 512;

  f32x4 acc[4][4];
#pragma unroll
  for (int i = 0; i < 4; ++i)
#pragma unroll
    for (int j = 0; j < 4; ++j) acc[i][j] = (f32x4){0.f, 0.f, 0.f, 0.f};

  gload_lds16(gA0, lA0); gload_lds16(gA1, lA1);
  gload_lds16(gW0, lW0); gload_lds16(gW1, lW1);

  for (int k0 = 0;;) {
    __syncthreads();
    bf16x8 af[4], bf[4];
#pragma unroll
    for (int i = 0; i < 4; ++i) {
      const int row = wm + i * 16 + col16;
      af[i] = *(const bf16x8*)(As + row * 32 + ((g ^ ((row >> 1) & 3)) * 8));
    }
#pragma unroll
    for (int j = 0; j < 4; ++j) {
      const int row = wn + j * 16 + col16;
      bf[j] = *(const bf16x8*)(Ws + row * 32 + ((g ^ ((row >> 1) & 3)) * 8));
    }
#pragma unroll
    for (int i = 0; i < 4; ++i)
#pragma unroll
      for (int j = 0; j < 4; ++j)
        acc[i][j] = __builtin_amdgcn_mfma_f32_16x16x32_bf16(af[i], bf[j], acc[i][j], 0, 0, 0);
    k0 += 32;
    if (k0 >= K) break;
    __syncthreads();
    gload_lds16(gA0 + k0, lA0); gload_lds16(gA1 + k0, lA1);
    gload_lds16(gW0 + k0, lW0); gload_lds16(gW1 + k0, lW1);
  }

#pragma unroll
  for (int i = 0; i < 4; ++i)
#pragma unroll
    for (int j = 0; j < 4; ++j) {
      const int col = wrow + wn + j * 16 + col16;
      if (col < N) {
        const int row0 = arow + wm + i * 16 + g * 4;
#pragma unroll
        for (int r = 0; r < 4; ++r) {
          if constexpr (BF16_OUT)
            ((unsigned short*)Cv)[(size_t)(row0 + r) * N + col] = f2u(acc[i][j][r]);
          else
            ((float*)Cv)[(size_t)(row0 + r) * N + col] = acc[i][j][r];
        }
      }
    }
}

// ---------------------------------------------------------------------------
// RMSNorm over last dim, f32 in -> bf16 out. (unchanged)
// ---------------------------------------------------------------------------
__global__ __launch_bounds__(256) void rmsnorm_kernel(const float* __restrict__ src, int src_ld,
                                                      const float* __restrict__ w,
                                                      unsigned short* __restrict__ dst, int dst_ld,
                                                      int dim) {
  const int row = blockIdx.x;
  const float* x = src + (size_t)row * src_ld;
  float ss = 0.f;
  for (int i = threadIdx.x; i < dim; i += 256) {
    float v = x[i];
    ss += v * v;
  }
#pragma unroll
  for (int off = 32; off; off >>= 1) ss += __shfl_xor(ss, off);
  __shared__ float red[4];
  const int wv = threadIdx.x >> 6, ln = threadIdx.x & 63;
  if (ln == 0) red[wv] = ss;
  __syncthreads();
  const float tot = red[0] + red[1] + red[2] + red[3];
  const float scale = rsqrtf(tot / (float)dim + 1e-6f);
  for (int i = threadIdx.x; i < dim; i += 256) {
    dst[(size_t)row * dst_ld + i] = f2u(w[i] * (x[i] * scale));
  }
}

// ---------------------------------------------------------------------------
// RoPE (unchanged)
// ---------------------------------------------------------------------------
__global__ void rope_kernel(unsigned short* __restrict__ q, const float* __restrict__ ckv,
                            unsigned short* __restrict__ kpe, const int* __restrict__ pos_ids) {
  const int s = blockIdx.x;
  const int j = threadIdx.x;  // 0..31
  const float t = (float)pos_ids[s];
  const float invf = powf(50000.0f, -(float)(2 * j) / 64.0f);
  const float ang = t * invf;
  const float c = cosf(ang), sn = sinf(ang);
  for (int h = 0; h < N_HEADS; ++h) {
    unsigned short* base = q + (size_t)s * (N_HEADS * QHD) + h * QHD + NOPE;
    const float x0 = u2f(base[2 * j]), x1 = u2f(base[2 * j + 1]);
    __syncthreads();
    base[j] = f2u(x0 * c - x1 * sn);
    base[32 + j] = f2u(x1 * c + x0 * sn);
    __syncthreads();
  }
  const float* kb = ckv + (size_t)s * (KV_LORA + ROPE_D) + KV_LORA;
  kpe[(size_t)s * ROPE_D + j] = f2u(kb[2 * j] * c - kb[2 * j + 1] * sn);
  kpe[(size_t)s * ROPE_D + 32 + j] = f2u(kb[2 * j + 1] * c + kb[2 * j] * sn);
}

// ---------------------------------------------------------------------------
// V transpose + PERMUTED column order: within each 32-column block, source
// column q is stored at position p(q) = 8*((q&15)>>2) + 4*((q>>4)&1) + (q&3),
// i.e. stored position p holds actual k = 4*(p>>3) + (p&3) + 16*((p>>2)&1) —
// exactly the per-lane k-order of the QK score fragment, so PV A-fragments
// become single contiguous 16B reads.
// ---------------------------------------------------------------------------
__global__ __launch_bounds__(256) void build_vt(const unsigned short* __restrict__ kv,
                                                unsigned short* __restrict__ Vt) {
  __shared__ unsigned short t[32][33];
  const int s0 = blockIdx.x * 32, d0 = blockIdx.y * 32, h = blockIdx.z;
  const int tx = threadIdx.x & 31, ty = threadIdx.x >> 5;
#pragma unroll
  for (int i = 0; i < 4; ++i) {
    const int s = s0 + ty + i * 8;
    t[ty + i * 8][tx] = kv[(size_t)s * (N_HEADS * 256) + h * 256 + NOPE + d0 + tx];
  }
  __syncthreads();
  const int p = ((tx & 15) >> 2) * 8 + ((tx >> 4) & 1) * 4 + (tx & 3);
#pragma unroll
  for (int i = 0; i < 4; ++i) {
    const int d = d0 + ty + i * 8;
    Vt[((size_t)h * VD + d) * S_LEN + s0 + p] = t[tx][ty + i * 8];
  }
}

// ---------------------------------------------------------------------------
// K pack: Kb(h, s, 0:192) = [kvbuf k_nope | kpe]. (unchanged)
// ---------------------------------------------------------------------------
__global__ __launch_bounds__(256) void build_k(const unsigned short* __restrict__ kv,
                                               const unsigned short* __restrict__ kpe,
                                               unsigned short* __restrict__ Kb) {
  const int c = blockIdx.x * 256 + threadIdx.x;  // 786432 chunks
  const int sh = c / 24, slot = c - sh * 24;
  const int h = sh >> 11, s = sh & 2047;
  const unsigned short* src = (slot < 16)
      ? kv + (size_t)s * (N_HEADS * 256) + h * 256 + slot * 8
      : kpe + (size_t)s * ROPE_D + (slot - 16) * 8;
  *(uint4*)(Kb + (size_t)c * 8) = *(const uint4*)src;
}

// ---------------------------------------------------------------------------
// MFMA flash attention. 64-k double-buffered LDS tiles (80 KB), 4 waves x
// 16 q rows. K LDS rows 384B with chunk^row XOR swizzle; V LDS rows 128B
// (permuted column order from build_vt) with slot^row XOR swizzle — both
// staged via linear-dest global_load_lds with pre-swizzled global sources,
// read back with the same XOR (canonical data, conflict-free banks).
// XCD swizzle: each XCD owns a head pair (K/V set 2.6MB < 4MB L2).
// ---------------------------------------------------------------------------
__global__ __launch_bounds__(256) void flash_attn(const unsigned short* __restrict__ Q,   // (S,3072) pre-scaled
                                                  const unsigned short* __restrict__ Kb,  // (H,S,192)
                                                  const unsigned short* __restrict__ Vt,  // (H,128,S) permuted
                                                  unsigned short* __restrict__ out) {     // (S,2048)
  __shared__ unsigned short Ks[2][64 * QHD];   // 2 x 24 KB
  __shared__ unsigned short Vs[2][VD * 64];    // 2 x 16 KB
  const int tid = threadIdx.x;
  const int wave = tid >> 6, lane = tid & 63;
  const int g = lane >> 4, col = lane & 15;
  const int lin = (int)blockIdx.x + ((int)blockIdx.y << 5);
  const int h = ((lin & 7) << 1) | ((lin >> 3) & 1);     // XCD(lin%8) owns heads {2x,2x+1}
  const int qtile = 31 - (lin >> 4);                     // heavy blocks dispatched first
  const int qw = qtile * 64 + wave * 16;
  const int qr = qw + col;

  bf16x8 qf[6];
  {
    const unsigned short* qrow = Q + (size_t)(qw + col) * (N_HEADS * QHD) + h * QHD + g * 8;
#pragma unroll
    for (int t = 0; t < 6; ++t) qf[t] = *(const bf16x8*)(qrow + t * 32);
  }

  const unsigned short* KbH = Kb + (size_t)h * S_LEN * QHD;
  const unsigned short* VtH = Vt + (size_t)h * VD * S_LEN;

  // staging source offsets (pre-swizzled slots; fixed across tiles)
  int eK[6], eV[4];
#pragma unroll
  for (int i = 0; i < 6; ++i) {                 // 1536 K chunks of 16B
    const int c = i * 256 + tid;
    const int r = c / 24, sl = c - r * 24;
    eK[i] = r * QHD + (((sl & 24) | ((sl & 7) ^ (r & 7)))) * 8;
  }
#pragma unroll
  for (int i = 0; i < 4; ++i) {                 // 1024 V chunks of 16B
    const int c = i * 256 + tid;
    const int d = c >> 3, sl = c & 7;
    eV[i] = d * S_LEN + ((sl ^ (d & 7))) * 8;
  }

  f32x4 o[8];
#pragma unroll
  for (int i = 0; i < 8; ++i) o[i] = (f32x4){0.f, 0.f, 0.f, 0.f};
  float m = -1e30f, l = 0.f;

  const int nT = qtile + 1;

  // prologue: stage tile 0 into buffer 0
#pragma unroll
  for (int i = 0; i < 6; ++i) gload_lds16(KbH + eK[i], &Ks[0][(i * 256 + wave * 64) * 8]);
#pragma unroll
  for (int i = 0; i < 4; ++i) gload_lds16(VtH + eV[i], &Vs[0][(i * 256 + wave * 64) * 8]);

  // ds_read swizzled slot offsets: ((4t+g) ^ (row&7)) * 8; row&7 == col&7
  int xK[6];
#pragma unroll
  for (int t = 0; t < 6; ++t) xK[t] = ((4 * t + g) ^ (col & 7)) * 8;
  const int rbK = col * QHD;
  const int rbV = col * 64;

  for (int tt = 0; tt < nT; ++tt) {
    __syncthreads();  // stage(tt) landed; prior reads of buf[(tt+1)&1] done
    if (tt + 1 < nT) {
      const unsigned short* kp = KbH + (size_t)(tt + 1) * 64 * QHD;
      const unsigned short* vp = VtH + (tt + 1) * 64;
      const int b = (tt + 1) & 1;
#pragma unroll
      for (int i = 0; i < 6; ++i) gload_lds16(kp + eK[i], &Ks[b][(i * 256 + wave * 64) * 8]);
#pragma unroll
      for (int i = 0; i < 4; ++i) gload_lds16(vp + eV[i], &Vs[b][(i * 256 + wave * 64) * 8]);
    }
    const unsigned short* Ksc = Ks[tt & 1];
    const unsigned short* Vsc = Vs[tt & 1];
    const int k0 = tt * 64;

    f32x4 c4[4];
#pragma unroll
    for (int f = 0; f < 4; ++f) c4[f] = (f32x4){0.f, 0.f, 0.f, 0.f};
    __builtin_amdgcn_s_setprio(1);
#pragma unroll
    for (int dt = 0; dt < 6; ++dt) {
#pragma unroll
      for (int f = 0; f < 4; ++f) {
        const bf16x8 a = *(const bf16x8*)(Ksc + rbK + f * 16 * QHD + xK[dt]);
        c4[f] = __builtin_amdgcn_mfma_f32_16x16x32_bf16(a, qf[dt], c4[f], 0, 0, 0);
      }
    }
    __builtin_amdgcn_s_setprio(0);

    // causal mask + online softmax (q = col; k = k0 + 16f + 4g + r)
    float sv[4][4];
#pragma unroll
    for (int f = 0; f < 4; ++f)
#pragma unroll
      for (int r = 0; r < 4; ++r) {
        const int kk = k0 + 16 * f + 4 * g + r;
        sv[f][r] = (kk <= qr) ? c4[f][r] : -1e30f;
      }
    float bm0 = fmaxf(fmaxf(fmaxf(sv[0][0], sv[0][1]), fmaxf(sv[0][2], sv[0][3])),
                      fmaxf(fmaxf(sv[1][0], sv[1][1]), fmaxf(sv[1][2], sv[1][3])));
    float bm1 = fmaxf(fmaxf(fmaxf(sv[2][0], sv[2][1]), fmaxf(sv[2][2], sv[2][3])),
                      fmaxf(fmaxf(sv[3][0], sv[3][1]), fmaxf(sv[3][2], sv[3][3])));
    float bm = fmaxf(bm0, bm1);
    bm = fmaxf(bm, __shfl_xor(bm, 16));
    bm = fmaxf(bm, __shfl_xor(bm, 32));
    const float mn = fmaxf(m, bm);
    const float corr = __expf(m - mn);
    float ps = 0.f;
    bf16x8 pb0, pb1;
#pragma unroll
    for (int f = 0; f < 4; ++f)
#pragma unroll
      for (int r = 0; r < 4; ++r) {
        const float p = __expf(sv[f][r] - mn);
        ps += p;
        if (f < 2) pb0[(f & 1) * 4 + r] = (short)f2u(p);
        else       pb1[(f & 1) * 4 + r] = (short)f2u(p);
      }
    ps += __shfl_xor(ps, 16);
    ps += __shfl_xor(ps, 32);
    l = l * corr + ps;
    m = mn;
#pragma unroll
    for (int i = 0; i < 8; ++i) {
      o[i][0] *= corr; o[i][1] *= corr; o[i][2] *= corr; o[i][3] *= corr;
    }
    __builtin_amdgcn_s_setprio(1);
#pragma unroll
    for (int db = 0; db < 8; ++db) {
      const bf16x8 va0 = *(const bf16x8*)(Vsc + db * 1024 + rbV + xK[0]);
      o[db] = __builtin_amdgcn_mfma_f32_16x16x32_bf16(va0, pb0, o[db], 0, 0, 0);
      const bf16x8 va1 = *(const bf16x8*)(Vsc + db * 1024 + rbV + xK[1]);
      o[db] = __builtin_amdgcn_mfma_f32_16x16x32_bf16(va1, pb1, o[db], 0, 0, 0);
    }
    __builtin_amdgcn_s_setprio(0);
  }

  const float inv = 1.f / l;
  unsigned short* orow = out + (size_t)(qw + col) * (N_HEADS * VD) + h * VD;
#pragma unroll
  for (int db = 0; db < 8; ++db)
#pragma unroll
    for (int r = 0; r < 4; ++r)
      orow[db * 16 + 4 * g + r] = f2u(o[db][r] * inv);
}

// ---------------------------------------------------------------------------
extern "C" void kernel_launch(void* const* d_in, const int* in_sizes, int n_in,
                              void* d_out, int out_size, void* d_ws, size_t ws_size,
                              hipStream_t stream) {
  const float* hidden    = (const float*)d_in[0];
  const int*   pos       = (const int*)d_in[1];
  const float* q_a_w     = (const float*)d_in[2];
  const float* q_a_ln_w  = (const float*)d_in[3];
  const float* q_b_w     = (const float*)d_in[4];
  const float* kv_a_w    = (const float*)d_in[5];
  const float* kv_a_ln_w = (const float*)d_in[6];
  const float* kv_b_w    = (const float*)d_in[7];
  const float* o_w       = (const float*)d_in[8];
  float* out = (float*)d_out;
  (void)in_sizes; (void)n_in; (void)out_size; (void)ws_size;

  // workspace layout (bytes, 256-aligned); total ~86 MB
  char* base = (char*)d_ws;
  unsigned short* qbuf  = (unsigned short*)(base);              // S*3072 bf16
  unsigned short* kvbuf = (unsigned short*)(base + 12582912);   // S*4096 bf16
  float*          ckv   = (float*)(base + 29360128);            // S*576 f32
  float*          qa    = (float*)(base + 34078720);            // S*1536 f32
  unsigned short* attnb = (unsigned short*)(base + 34078720);   //   overlay (qa dead)
  unsigned short* qan   = (unsigned short*)(base + 46661632);   // S*1536 bf16
  unsigned short* ckvn  = (unsigned short*)(base + 52953088);   // S*512 bf16
  unsigned short* Hb    = (unsigned short*)(base + 55050240);   // S*2048 bf16
  unsigned short* Vt    = (unsigned short*)(base + 55050240);   //   overlay (Hb dead)
  unsigned short* wbuf  = (unsigned short*)(base + 63438848);   // 4.72M bf16
  unsigned short* kpe   = (unsigned short*)(base + 72876032);   // S*64 bf16
  unsigned short* Kb    = (unsigned short*)(base + 73400320);   // 16*S*192 bf16

  const dim3 b256(256);
  const float qscale = 0.07216878364870323f;  // 192^-0.5, folded into q_b_w

  conv_bf16<<<2048, b256, 0, stream>>>(hidden, Hb, (S_LEN * D_MODEL) / 4, 1.f);

  conv_bf16<<<2048, b256, 0, stream>>>(q_a_w, wbuf, (Q_LORA * D_MODEL) / 4, 1.f);
  gemm_mfma<false><<<dim3(Q_LORA / 128, S_LEN / 128), b256, 0, stream>>>(Hb, wbuf, qa, Q_LORA, D_MODEL);
  rmsnorm_kernel<<<S_LEN, b256, 0, stream>>>(qa, Q_LORA, q_a_ln_w, qan, Q_LORA, Q_LORA);

  conv_bf16<<<2048, b256, 0, stream>>>(q_b_w, wbuf, (N_HEADS * QHD * Q_LORA) / 4, qscale);
  gemm_mfma<true><<<dim3(N_HEADS * QHD / 128, S_LEN / 128), b256, 0, stream>>>(qan, wbuf, qbuf, N_HEADS * QHD, Q_LORA);

  conv_bf16<<<2048, b256, 0, stream>>>(kv_a_w, wbuf, ((KV_LORA + ROPE_D) * D_MODEL) / 4, 1.f);
  gemm_mfma<false><<<dim3(5, S_LEN / 128), b256, 0, stream>>>(Hb, wbuf, ckv, KV_LORA + ROPE_D, D_MODEL);
  rmsnorm_kernel<<<S_LEN, b256, 0, stream>>>(ckv, KV_LORA + ROPE_D, kv_a_ln_w, ckvn, KV_LORA, KV_LORA);

  rope_kernel<<<S_LEN, 32, 0, stream>>>(qbuf, ckv, kpe, pos);

  conv_bf16<<<2048, b256, 0, stream>>>(kv_b_w, wbuf, (N_HEADS * 256 * KV_LORA) / 4, 1.f);
  gemm_mfma<true><<<dim3(N_HEADS * 256 / 128, S_LEN / 128), b256, 0, stream>>>(ckvn, wbuf, kvbuf, N_HEADS * 256, KV_LORA);

  build_vt<<<dim3(S_LEN / 32, VD / 32, N_HEADS), b256, 0, stream>>>(kvbuf, Vt);
  build_k<<<3072, b256, 0, stream>>>(kvbuf, kpe, Kb);
  flash_attn<<<dim3(S_LEN / 64, N_HEADS), b256, 0, stream>>>(qbuf, Kb, Vt, attnb);

  conv_bf16<<<2048, b256, 0, stream>>>(o_w, wbuf, (D_MODEL * N_HEADS * VD) / 4, 1.f);
  gemm_mfma<false><<<dim3(D_MODEL / 128, S_LEN / 128), b256, 0, stream>>>(attnb, wbuf, out, D_MODEL, N_HEADS * VD);
}

// Round 6
// 257.725 us; speedup vs baseline: 17.7222x; 1.0849x over previous
//
#include <hip/hip_runtime.h>
#include <hip/hip_bf16.h>
#include <cmath>

#define S_LEN 2048
#define D_MODEL 2048
#define N_HEADS 16
#define Q_LORA 1536
#define KV_LORA 512
#define NOPE 128
#define ROPE_D 64
#define VD 128
#define QHD 192
#define AC_W 2112  // fused a-proj output width: 1536 q_a + 576 ckv

typedef __attribute__((ext_vector_type(8))) short bf16x8;
typedef __attribute__((ext_vector_type(4))) float f32x4;
typedef __attribute__((ext_vector_type(4))) unsigned short u16x4;

static __device__ __forceinline__ unsigned short f2u(float x) {
  union { float f; unsigned u; } v; v.f = x;
  unsigned r = v.u + 0x7fffu + ((v.u >> 16) & 1u);  // RNE
  return (unsigned short)(r >> 16);
}
static __device__ __forceinline__ unsigned short f2u_fast(float x) {  // round-half-up, x>=0
  union { float f; unsigned u; } v; v.f = x;
  return (unsigned short)((v.u + 0x8000u) >> 16);
}
static __device__ __forceinline__ float u2f(unsigned short x) {
  union { unsigned u; float f; } v; v.u = ((unsigned)x) << 16;
  return v.f;
}

#define AS1 __attribute__((address_space(1)))
#define AS3 __attribute__((address_space(3)))
static __device__ __forceinline__ void gload_lds16(const unsigned short* g, unsigned short* l) {
  __builtin_amdgcn_global_load_lds((const AS1 unsigned int*)g, (AS3 unsigned int*)l, 16, 0, 0);
}

// ---------------------------------------------------------------------------
// f32 -> bf16 convert (optionally scaled). n4 = elements/4.
// ---------------------------------------------------------------------------
__global__ __launch_bounds__(256) void conv_bf16(const float* __restrict__ src,
                                                 unsigned short* __restrict__ dst,
                                                 int n4, float scale) {
  for (int i = blockIdx.x * 256 + threadIdx.x; i < n4; i += gridDim.x * 256) {
    const float4 v = ((const float4*)src)[i];
    u16x4 o;
    o[0] = f2u(v.x * scale); o[1] = f2u(v.y * scale);
    o[2] = f2u(v.z * scale); o[3] = f2u(v.w * scale);
    ((u16x4*)dst)[i] = o;
  }
}

// ---------------------------------------------------------------------------
// bf16 MFMA GEMM: C[M,N] = A[M,K] @ W[N,K]^T. 128x128 tile, BK=32, 4 waves,
// DOUBLE-buffered LDS (one barrier per K-step; stage(t+1) issued right after
// the barrier, lands during this step's ds_read+MFMA). XOR-swizzled k-slots
// (pre-swizzled global source, same XOR on ds_read).
// MODE 0: f32 C. MODE 1: bf16 C. MODE 2: kv-split — col=h*256+d; d<128 goes
// to C2 = Kb(h,row,d), d>=128 goes to Cv = kvbuf(row,col) [bf16].
// ---------------------------------------------------------------------------
template <int MODE>
__global__ __launch_bounds__(256) void gemm_mfma(const unsigned short* __restrict__ A,
                                                 const unsigned short* __restrict__ W,
                                                 void* __restrict__ Cv,
                                                 unsigned short* __restrict__ C2,
                                                 int N, int K) {
  __shared__ unsigned short As[2][4096];
  __shared__ unsigned short Ws[2][4096];
  const int tid = threadIdx.x;
  const int wave = tid >> 6, lane = tid & 63;
  const int col16 = lane & 15, g = lane >> 4;
  const int arow = blockIdx.y * 128, wrow = blockIdx.x * 128;
  const int wm = (wave >> 1) * 64, wn = (wave & 1) * 64;

  const int c0 = tid, c1 = 256 + tid;
  const int rA0 = c0 >> 2, rA1 = c1 >> 2;
  const int ko0 = ((c0 & 3) ^ ((rA0 >> 1) & 3)) * 8;
  const int ko1 = ((c1 & 3) ^ ((rA1 >> 1) & 3)) * 8;
  const unsigned short* gA0 = A + (size_t)(arow + rA0) * K + ko0;
  const unsigned short* gA1 = A + (size_t)(arow + rA1) * K + ko1;
  const int wr0 = (wrow + rA0 < N) ? wrow + rA0 : N - 1;
  const int wr1 = (wrow + rA1 < N) ? wrow + rA1 : N - 1;
  const unsigned short* gW0 = W + (size_t)wr0 * K + ko0;
  const unsigned short* gW1 = W + (size_t)wr1 * K + ko1;

  f32x4 acc[4][4];
#pragma unroll
  for (int i = 0; i < 4; ++i)
#pragma unroll
    for (int j = 0; j < 4; ++j) acc[i][j] = (f32x4){0.f, 0.f, 0.f, 0.f};

  // prologue: stage k=0 into buffer 0
  gload_lds16(gA0, &As[0][wave * 512]); gload_lds16(gA1, &As[0][2048 + wave * 512]);
  gload_lds16(gW0, &Ws[0][wave * 512]); gload_lds16(gW1, &Ws[0][2048 + wave * 512]);

  int cur = 0;
  for (int k0 = 0; k0 < K; k0 += 32) {
    __syncthreads();  // buf[cur] staged; prior reads of buf[cur^1] drained
    if (k0 + 32 < K) {
      const int b = cur ^ 1, kk = k0 + 32;
      gload_lds16(gA0 + kk, &As[b][wave * 512]); gload_lds16(gA1 + kk, &As[b][2048 + wave * 512]);
      gload_lds16(gW0 + kk, &Ws[b][wave * 512]); gload_lds16(gW1 + kk, &Ws[b][2048 + wave * 512]);
    }
    bf16x8 af[4], bfr[4];
#pragma unroll
    for (int i = 0; i < 4; ++i) {
      const int row = wm + i * 16 + col16;
      af[i] = *(const bf16x8*)(&As[cur][row * 32 + ((g ^ ((row >> 1) & 3)) * 8)]);
    }
#pragma unroll
    for (int j = 0; j < 4; ++j) {
      const int row = wn + j * 16 + col16;
      bfr[j] = *(const bf16x8*)(&Ws[cur][row * 32 + ((g ^ ((row >> 1) & 3)) * 8)]);
    }
#pragma unroll
    for (int i = 0; i < 4; ++i)
#pragma unroll
      for (int j = 0; j < 4; ++j)
        acc[i][j] = __builtin_amdgcn_mfma_f32_16x16x32_bf16(af[i], bfr[j], acc[i][j], 0, 0, 0);
    cur ^= 1;
  }

#pragma unroll
  for (int i = 0; i < 4; ++i)
#pragma unroll
    for (int j = 0; j < 4; ++j) {
      const int col = wrow + wn + j * 16 + col16;
      if (col < N) {
        const int row0 = arow + wm + i * 16 + g * 4;
#pragma unroll
        for (int r = 0; r < 4; ++r) {
          if constexpr (MODE == 0)
            ((float*)Cv)[(size_t)(row0 + r) * N + col] = acc[i][j][r];
          else if constexpr (MODE == 1)
            ((unsigned short*)Cv)[(size_t)(row0 + r) * N + col] = f2u(acc[i][j][r]);
          else {
            const int hh = col >> 8, d = col & 255;
            if (d < NOPE)
              C2[((size_t)hh * S_LEN + row0 + r) * QHD + d] = f2u(acc[i][j][r]);
            else
              ((unsigned short*)Cv)[(size_t)(row0 + r) * (N_HEADS * 256) + col] = f2u(acc[i][j][r]);
          }
        }
      }
    }
}

// ---------------------------------------------------------------------------
// RMSNorm over last dim, f32 in -> bf16 out.
// ---------------------------------------------------------------------------
__global__ __launch_bounds__(256) void rmsnorm_kernel(const float* __restrict__ src, int src_ld,
                                                      const float* __restrict__ w,
                                                      unsigned short* __restrict__ dst, int dst_ld,
                                                      int dim) {
  const int row = blockIdx.x;
  const float* x = src + (size_t)row * src_ld;
  float ss = 0.f;
  for (int i = threadIdx.x; i < dim; i += 256) {
    float v = x[i];
    ss += v * v;
  }
#pragma unroll
  for (int off = 32; off; off >>= 1) ss += __shfl_xor(ss, off);
  __shared__ float red[4];
  const int wv = threadIdx.x >> 6, ln = threadIdx.x & 63;
  if (ln == 0) red[wv] = ss;
  __syncthreads();
  const float tot = red[0] + red[1] + red[2] + red[3];
  const float scale = rsqrtf(tot / (float)dim + 1e-6f);
  for (int i = threadIdx.x; i < dim; i += 256) {
    dst[(size_t)row * dst_ld + i] = f2u(w[i] * (x[i] * scale));
  }
}

// ---------------------------------------------------------------------------
// RoPE: q_pe slices of bf16 qbuf in place; k_pe from f32 ac -> broadcast into
// all 16 heads of Kb (cols 128..192).
// ---------------------------------------------------------------------------
__global__ void rope_kernel(unsigned short* __restrict__ q, const float* __restrict__ ac,
                            unsigned short* __restrict__ Kb, const int* __restrict__ pos_ids) {
  const int s = blockIdx.x;
  const int j = threadIdx.x;  // 0..31
  const float t = (float)pos_ids[s];
  const float invf = powf(50000.0f, -(float)(2 * j) / 64.0f);
  const float ang = t * invf;
  const float c = cosf(ang), sn = sinf(ang);
  for (int h = 0; h < N_HEADS; ++h) {
    unsigned short* base = q + (size_t)s * (N_HEADS * QHD) + h * QHD + NOPE;
    const float x0 = u2f(base[2 * j]), x1 = u2f(base[2 * j + 1]);
    __syncthreads();
    base[j] = f2u(x0 * c - x1 * sn);
    base[32 + j] = f2u(x1 * c + x0 * sn);
    __syncthreads();
  }
  const float* kb = ac + (size_t)s * AC_W + 2048;
  const unsigned short r0 = f2u(kb[2 * j] * c - kb[2 * j + 1] * sn);
  const unsigned short r1 = f2u(kb[2 * j + 1] * c + kb[2 * j] * sn);
#pragma unroll
  for (int h = 0; h < N_HEADS; ++h) {
    unsigned short* kd = Kb + ((size_t)h * S_LEN + s) * QHD + NOPE;
    kd[j] = r0;
    kd[32 + j] = r1;
  }
}

// ---------------------------------------------------------------------------
// V transpose + PERMUTED column order (PV fragment order), unchanged.
// ---------------------------------------------------------------------------
__global__ __launch_bounds__(256) void build_vt(const unsigned short* __restrict__ kv,
                                                unsigned short* __restrict__ Vt) {
  __shared__ unsigned short t[32][33];
  const int s0 = blockIdx.x * 32, d0 = blockIdx.y * 32, h = blockIdx.z;
  const int tx = threadIdx.x & 31, ty = threadIdx.x >> 5;
#pragma unroll
  for (int i = 0; i < 4; ++i) {
    const int s = s0 + ty + i * 8;
    t[ty + i * 8][tx] = kv[(size_t)s * (N_HEADS * 256) + h * 256 + NOPE + d0 + tx];
  }
  __syncthreads();
  const int p = ((tx & 15) >> 2) * 8 + ((tx >> 4) & 1) * 4 + (tx & 3);
#pragma unroll
  for (int i = 0; i < 4; ++i) {
    const int d = d0 + ty + i * 8;
    Vt[((size_t)h * VD + d) * S_LEN + s0 + p] = t[tx][ty + i * 8];
  }
}

// ---------------------------------------------------------------------------
// MFMA flash attention. 64-k double-buffered LDS tiles, 4 waves x 16 q rows.
// exp2-domain softmax (log2e folded into Q prescale), defer-max THR=8,
// mask only on diagonal tiles. Work-balanced (qtile,h) mapping: CU pair
// (lin, lin+256) sums to 33 tile-iters; XCD x owns heads {2x, 2x+1}.
// ---------------------------------------------------------------------------
__global__ __launch_bounds__(256) void flash_attn(const unsigned short* __restrict__ Q,   // (S,3072) pre-scaled
                                                  const unsigned short* __restrict__ Kb,  // (H,S,192)
                                                  const unsigned short* __restrict__ Vt,  // (H,128,S) permuted
                                                  unsigned short* __restrict__ out) {     // (S,2048)
  __shared__ unsigned short Ks[2][64 * QHD];   // 2 x 24 KB
  __shared__ unsigned short Vs[2][VD * 64];    // 2 x 16 KB
  const int tid = threadIdx.x;
  const int wave = tid >> 6, lane = tid & 63;
  const int g = lane >> 4, col = lane & 15;
  const int lin = (int)blockIdx.x + ((int)blockIdx.y << 5);
  const int h = ((lin & 7) << 1) | ((lin >> 3) & 1);
  const int z = lin >> 4;                                // 0..31
  const int qtile = (z < 16) ? (31 - z) : (z - 16);      // balanced pairing
  const int qw = qtile * 64 + wave * 16;
  const int qr = qw + col;

  bf16x8 qf[6];
  {
    const unsigned short* qrow = Q + (size_t)(qw + col) * (N_HEADS * QHD) + h * QHD + g * 8;
#pragma unroll
    for (int t = 0; t < 6; ++t) qf[t] = *(const bf16x8*)(qrow + t * 32);
  }

  const unsigned short* KbH = Kb + (size_t)h * S_LEN * QHD;
  const unsigned short* VtH = Vt + (size_t)h * VD * S_LEN;

  int eK[6], eV[4];
#pragma unroll
  for (int i = 0; i < 6; ++i) {
    const int c = i * 256 + tid;
    const int r = c / 24, sl = c - r * 24;
    eK[i] = r * QHD + (((sl & 24) | ((sl & 7) ^ (r & 7)))) * 8;
  }
#pragma unroll
  for (int i = 0; i < 4; ++i) {
    const int c = i * 256 + tid;
    const int d = c >> 3, sl = c & 7;
    eV[i] = d * S_LEN + ((sl ^ (d & 7))) * 8;
  }

  f32x4 o[8];
#pragma unroll
  for (int i = 0; i < 8; ++i) o[i] = (f32x4){0.f, 0.f, 0.f, 0.f};
  float m = -1e30f, l = 0.f;

  const int nT = qtile + 1;

#pragma unroll
  for (int i = 0; i < 6; ++i) gload_lds16(KbH + eK[i], &Ks[0][(i * 256 + wave * 64) * 8]);
#pragma unroll
  for (int i = 0; i < 4; ++i) gload_lds16(VtH + eV[i], &Vs[0][(i * 256 + wave * 64) * 8]);

  int xK[6];
#pragma unroll
  for (int t = 0; t < 6; ++t) xK[t] = ((4 * t + g) ^ (col & 7)) * 8;
  const int rbK = col * QHD;
  const int rbV = col * 64;

  for (int tt = 0; tt < nT; ++tt) {
    __syncthreads();
    if (tt + 1 < nT) {
      const unsigned short* kp = KbH + (size_t)(tt + 1) * 64 * QHD;
      const unsigned short* vp = VtH + (tt + 1) * 64;
      const int b = (tt + 1) & 1;
#pragma unroll
      for (int i = 0; i < 6; ++i) gload_lds16(kp + eK[i], &Ks[b][(i * 256 + wave * 64) * 8]);
#pragma unroll
      for (int i = 0; i < 4; ++i) gload_lds16(vp + eV[i], &Vs[b][(i * 256 + wave * 64) * 8]);
    }
    const unsigned short* Ksc = Ks[tt & 1];
    const unsigned short* Vsc = Vs[tt & 1];
    const int k0 = tt * 64;

    f32x4 c4[4];
#pragma unroll
    for (int f = 0; f < 4; ++f) c4[f] = (f32x4){0.f, 0.f, 0.f, 0.f};
    __builtin_amdgcn_s_setprio(1);
#pragma unroll
    for (int dt = 0; dt < 6; ++dt) {
#pragma unroll
      for (int f = 0; f < 4; ++f) {
        const bf16x8 a = *(const bf16x8*)(Ksc + rbK + f * 16 * QHD + xK[dt]);
        c4[f] = __builtin_amdgcn_mfma_f32_16x16x32_bf16(a, qf[dt], c4[f], 0, 0, 0);
      }
    }
    __builtin_amdgcn_s_setprio(0);

    // scores in log2 domain; mask only needed on diagonal tiles
    float sv[4][4];
    if (k0 + 63 > qw) {
#pragma unroll
      for (int f = 0; f < 4; ++f)
#pragma unroll
        for (int r = 0; r < 4; ++r) {
          const int kk = k0 + 16 * f + 4 * g + r;
          sv[f][r] = (kk <= qr) ? c4[f][r] : -1e30f;
        }
    } else {
#pragma unroll
      for (int f = 0; f < 4; ++f)
#pragma unroll
        for (int r = 0; r < 4; ++r) sv[f][r] = c4[f][r];
    }
    float bm0 = fmaxf(fmaxf(fmaxf(sv[0][0], sv[0][1]), fmaxf(sv[0][2], sv[0][3])),
                      fmaxf(fmaxf(sv[1][0], sv[1][1]), fmaxf(sv[1][2], sv[1][3])));
    float bm1 = fmaxf(fmaxf(fmaxf(sv[2][0], sv[2][1]), fmaxf(sv[2][2], sv[2][3])),
                      fmaxf(fmaxf(sv[3][0], sv[3][1]), fmaxf(sv[3][2], sv[3][3])));
    float bm = fmaxf(bm0, bm1);
    bm = fmaxf(bm, __shfl_xor(bm, 16));
    bm = fmaxf(bm, __shfl_xor(bm, 32));

    const bool skip = __all(bm <= m + 8.f);   // defer-max: p bounded by 2^8
    const float mn = skip ? m : fmaxf(m, bm);
    float ps = 0.f;
    bf16x8 pb0, pb1;
#pragma unroll
    for (int f = 0; f < 4; ++f)
#pragma unroll
      for (int r = 0; r < 4; ++r) {
        const float p = exp2f(sv[f][r] - mn);
        ps += p;
        if (f < 2) pb0[(f & 1) * 4 + r] = (short)f2u_fast(p);
        else       pb1[(f & 1) * 4 + r] = (short)f2u_fast(p);
      }
    ps += __shfl_xor(ps, 16);
    ps += __shfl_xor(ps, 32);
    if (skip) {
      l += ps;
    } else {
      const float corr = exp2f(m - mn);
      l = l * corr + ps;
      m = mn;
#pragma unroll
      for (int i = 0; i < 8; ++i) {
        o[i][0] *= corr; o[i][1] *= corr; o[i][2] *= corr; o[i][3] *= corr;
      }
    }
    __builtin_amdgcn_s_setprio(1);
#pragma unroll
    for (int db = 0; db < 8; ++db) {
      const bf16x8 va0 = *(const bf16x8*)(Vsc + db * 1024 + rbV + xK[0]);
      o[db] = __builtin_amdgcn_mfma_f32_16x16x32_bf16(va0, pb0, o[db], 0, 0, 0);
      const bf16x8 va1 = *(const bf16x8*)(Vsc + db * 1024 + rbV + xK[1]);
      o[db] = __builtin_amdgcn_mfma_f32_16x16x32_bf16(va1, pb1, o[db], 0, 0, 0);
    }
    __builtin_amdgcn_s_setprio(0);
  }

  const float inv = 1.f / l;
  unsigned short* orow = out + (size_t)(qw + col) * (N_HEADS * VD) + h * VD;
#pragma unroll
  for (int db = 0; db < 8; ++db)
#pragma unroll
    for (int r = 0; r < 4; ++r)
      orow[db * 16 + 4 * g + r] = f2u(o[db][r] * inv);
}

// ---------------------------------------------------------------------------
extern "C" void kernel_launch(void* const* d_in, const int* in_sizes, int n_in,
                              void* d_out, int out_size, void* d_ws, size_t ws_size,
                              hipStream_t stream) {
  const float* hidden    = (const float*)d_in[0];
  const int*   pos       = (const int*)d_in[1];
  const float* q_a_w     = (const float*)d_in[2];
  const float* q_a_ln_w  = (const float*)d_in[3];
  const float* q_b_w     = (const float*)d_in[4];
  const float* kv_a_w    = (const float*)d_in[5];
  const float* kv_a_ln_w = (const float*)d_in[6];
  const float* kv_b_w    = (const float*)d_in[7];
  const float* o_w       = (const float*)d_in[8];
  float* out = (float*)d_out;
  (void)in_sizes; (void)n_in; (void)out_size; (void)ws_size;

  // workspace layout (bytes); total ~94 MB
  char* base = (char*)d_ws;
  unsigned short* qbuf  = (unsigned short*)(base);              // S*3072 bf16  12.58MB
  unsigned short* kvbuf = (unsigned short*)(base + 12582912);   // S*4096 bf16  16.78MB (V half only)
  float*          ac    = (float*)(base + 29360128);            // S*2112 f32   17.30MB
  unsigned short* qan   = (unsigned short*)(base + 46661632);   // S*1536 bf16   6.29MB
  unsigned short* ckvn  = (unsigned short*)(base + 52953088);   // S*512 bf16    2.10MB
  unsigned short* Hb    = (unsigned short*)(base + 55050240);   // S*2048 bf16   8.39MB
  unsigned short* Vt    = (unsigned short*)(base + 55050240);   //   overlay (Hb dead after a-proj)
  unsigned short* wbuf  = (unsigned short*)(base + 63438848);   // 4.72M bf16    9.44MB
  unsigned short* attnb = (unsigned short*)(base + 72876032);   // S*2048 bf16   8.39MB
  unsigned short* Kb    = (unsigned short*)(base + 81264640);   // 16*S*192 bf16 12.58MB

  const dim3 b256(256);
  // 192^-0.5 * log2(e): scores come out of QK^T directly in log2 domain
  const float qscale = 0.07216878364870323f * 1.4426950408889634f;

  conv_bf16<<<2048, b256, 0, stream>>>(hidden, Hb, (S_LEN * D_MODEL) / 4, 1.f);

  // fused a-proj: W = [q_a_w ; kv_a_w] (2112 x 2048), C = ac f32 (S x 2112)
  conv_bf16<<<2048, b256, 0, stream>>>(q_a_w, wbuf, (Q_LORA * D_MODEL) / 4, 1.f);
  conv_bf16<<<1024, b256, 0, stream>>>(kv_a_w, wbuf + Q_LORA * D_MODEL,
                                       ((KV_LORA + ROPE_D) * D_MODEL) / 4, 1.f);
  gemm_mfma<0><<<dim3(17, S_LEN / 128), b256, 0, stream>>>(Hb, wbuf, ac, nullptr, AC_W, D_MODEL);

  rmsnorm_kernel<<<S_LEN, b256, 0, stream>>>(ac, AC_W, q_a_ln_w, qan, Q_LORA, Q_LORA);
  rmsnorm_kernel<<<S_LEN, b256, 0, stream>>>(ac + Q_LORA, AC_W, kv_a_ln_w, ckvn, KV_LORA, KV_LORA);

  // qbuf = qan @ (qscale*q_b_w)^T   (bf16 out)
  conv_bf16<<<2048, b256, 0, stream>>>(q_b_w, wbuf, (N_HEADS * QHD * Q_LORA) / 4, qscale);
  gemm_mfma<1><<<dim3(N_HEADS * QHD / 128, S_LEN / 128), b256, 0, stream>>>(qan, wbuf, qbuf, nullptr, N_HEADS * QHD, Q_LORA);

  // kv_b: k_nope -> Kb directly, values -> kvbuf
  conv_bf16<<<2048, b256, 0, stream>>>(kv_b_w, wbuf, (N_HEADS * 256 * KV_LORA) / 4, 1.f);
  gemm_mfma<2><<<dim3(N_HEADS * 256 / 128, S_LEN / 128), b256, 0, stream>>>(ckvn, wbuf, kvbuf, Kb, N_HEADS * 256, KV_LORA);

  // rope: qbuf q_pe in place; k_pe -> Kb cols 128..192 (all heads)
  rope_kernel<<<S_LEN, 32, 0, stream>>>(qbuf, ac, Kb, pos);

  build_vt<<<dim3(S_LEN / 32, VD / 32, N_HEADS), b256, 0, stream>>>(kvbuf, Vt);
  flash_attn<<<dim3(S_LEN / 64, N_HEADS), b256, 0, stream>>>(qbuf, Kb, Vt, attnb);

  conv_bf16<<<2048, b256, 0, stream>>>(o_w, wbuf, (D_MODEL * N_HEADS * VD) / 4, 1.f);
  gemm_mfma<0><<<dim3(D_MODEL / 128, S_LEN / 128), b256, 0, stream>>>(attnb, wbuf, out, nullptr, D_MODEL, N_HEADS * VD);
}